// Round 9
// baseline (320.495 us; speedup 1.0000x reference)
//
#include <hip/hip_runtime.h>

// Attention_Critic on MI355X — round 18: fused encoder+attention v2 (7 barriers).
//  - k_fused2: full-width bounce tiles aliased onto the two 34.8KB tiles:
//    A: sanb -> E -> KEYt (all heads, interleaved rows)
//    Bt: SE -> SELt -> VALt (transposed)
//    SEL/KEY/VAL are single K=128 N=128 reg-accumulated GEMMs (aSL/aK/aV live
//    together, ~96 VGPR); ONE barrier after all tile reads, ONE after tile
//    writes, ONE pair around SELt->saf extraction. Attention runs barrier-free
//    on stable tiles (attn2's proven code). 19 barriers (v1) -> 7.
//  - k_prep2 / k_fin / k_critic2: byte-identical to round 16.
//
// ws layout (bytes):
//   [0,256)          int flag (1 = bf16 inputs, 0 = f32)
//   [1024,+1310720)  stats partials f32 [8][256][160]
//   [1311744,+5120)  mst_g f32 [8][80][2]
//   [1316864,...)    Wsa_t bf16 [8][128 col][104 k]
//   [1529856,...)    Wse_t bf16 [8][128 col][72 k]
//   [1677312,...)    Wp_t  bf16 [3 mat][128 col][136 k]  (mat 0=sel,1=key,2=val)
//   [1781760,...)    Wc1t  bf16 [8][128 col][256 k]
//   [2306048,+32M)   SE   bf16 [8][16384][128]           (agent-major)
//   [+32M,+64M)      OT2  bf16 [16384*8][128] row=b*8+agent

typedef unsigned short u16;
typedef unsigned int u32;

#define NA 8
#define BATCH 16384
#define SD 64
#define AD 16
#define IND 80
#define HID 128
#define HEADS 4
#define ATT 32
#define EPS 1e-5f
#define KP 136    // u16 stride, 128-k tiles (16B-aligned rows)
#define KP3 104   // u16 stride, 96-k tiles (Wsa_t)
#define KPS 72    // u16 stride, 64-k tiles (Wse_t)
#define WBS 24    // u16 stride, softmax weight tiles

using short8 = __attribute__((ext_vector_type(8))) short;
using float4f = __attribute__((ext_vector_type(4))) float;
using uint4v = __attribute__((ext_vector_type(4))) u32;
#define MFMA16(a, b, c) __builtin_amdgcn_mfma_f32_16x16x32_bf16((a), (b), (c), 0, 0, 0)

__device__ __forceinline__ float bf2f(u16 u) { union { u32 i; float f; } v; v.i = ((u32)u) << 16; return v.f; }
__device__ __forceinline__ float lo2f(u32 w) { union { u32 i; float f; } v; v.i = w << 16; return v.f; }
__device__ __forceinline__ float hi2f(u32 w) { union { u32 i; float f; } v; v.i = w & 0xffff0000u; return v.f; }
__device__ __forceinline__ u16 f2bf(float f) {
  union { float f; u32 i; } v; v.f = f;
  u32 x = v.i;
  x += 0x7fffu + ((x >> 16) & 1u);   // RNE
  return (u16)(x >> 16);
}
__device__ __forceinline__ float lrelu(float x) { return x > 0.f ? x : 0.01f * x; }
__device__ __forceinline__ float ldin(const void* p, size_t i, bool bf) {
  return bf ? bf2f(((const u16*)p)[i]) : ((const float*)p)[i];
}
__device__ __forceinline__ u16 ldbf(const void* p, size_t i, bool bf) {
  return bf ? ((const u16*)p)[i] : f2bf(((const float*)p)[i]);
}
__device__ __forceinline__ short8 lds_s8(const u16* p) {   // 16B LDS load, 4B-aligned ok
  union { short8 v; u32 u[4]; } t;
  const u32* q = (const u32*)p;
  t.u[0] = q[0]; t.u[1] = q[1]; t.u[2] = q[2]; t.u[3] = q[3];
  return t.v;
}
// Barrier that orders LDS only: global stores stay in flight.
__device__ __forceinline__ void barlg() {
  asm volatile("s_waitcnt lgkmcnt(0)" ::: "memory");
  __builtin_amdgcn_s_barrier();
}

// ---------------- K1: merged BN stats (2048 blocks) + weight prep (60 blocks) ----------------
__global__ __launch_bounds__(256) void k_prep2(
    const void* __restrict__ s, const void* __restrict__ a,
    const void* __restrict__ Wsa, const void* __restrict__ Wse,
    const void* __restrict__ Wsl, const void* __restrict__ Wk, const void* __restrict__ Wv,
    const void* __restrict__ Wc1,
    int* __restrict__ flag, float* __restrict__ part,
    u16* __restrict__ Wsa_t, u16* __restrict__ Wse_t, u16* __restrict__ Wp_t, u16* __restrict__ Wc1t) {
  __shared__ u16 T[80 * 130];
  __shared__ float S0[256], Q0[256], S1[256], Q1[256];
  __shared__ int cnt[2];
  int tid = threadIdx.x;
  if (tid < 2) cnt[tid] = 0;
  __syncthreads();
  {   // local dtype detection (all blocks, first 1KB of s)
    u32 wv = ((const u32*)s)[tid];
    u32 lo = wv & 0xffffu, e = (lo >> 7) & 0xffu;
    if (lo == 0u || lo == 0x8000u) atomicAdd(&cnt[1], 1);
    else if (e < 0x70u || e > 0x8fu) atomicAdd(&cnt[0], 1);
  }
  __syncthreads();
  bool bf = !(cnt[0] >= 64 || cnt[1] >= 192);
  if (blockIdx.x == 0 && tid == 0) *flag = bf ? 1 : 0;
  int blkr = blockIdx.x;
  if (blkr < 2048) {   // ---- stats chunk: 64 rows ----
    int n = blkr >> 8, c = blkr & 255, b0 = c << 6;
    float* p = part + (size_t)(n * 256 + c) * 160;
    {
      int f2 = tid & 31, rg = tid >> 5;          // 8 row-groups
      float s0 = 0.f, s1 = 0.f, q0 = 0.f, q1 = 0.f;
      #pragma unroll
      for (int i = 0; i < 8; i++) {
        int b = b0 + rg + 8 * i;
        float x0, x1;
        if (bf) { u32 wv = ((const u32*)s)[((size_t)n * BATCH + b) * 32 + f2]; x0 = lo2f(wv); x1 = hi2f(wv); }
        else { const float* sf = (const float*)s + ((size_t)n * BATCH + b) * 64 + 2 * f2; x0 = sf[0]; x1 = sf[1]; }
        s0 += x0; q0 += x0 * x0; s1 += x1; q1 += x1 * x1;
      }
      S0[tid] = s0; Q0[tid] = q0; S1[tid] = s1; Q1[tid] = q1;
    }
    __syncthreads();
    if (tid < 64) {
      int f2 = tid >> 1, odd = tid & 1;
      float S = 0.f, Q = 0.f;
      #pragma unroll
      for (int rg = 0; rg < 8; rg++) {
        int ix = rg * 32 + f2;
        S += odd ? S1[ix] : S0[ix];
        Q += odd ? Q1[ix] : Q0[ix];
      }
      p[tid * 2] = S; p[tid * 2 + 1] = Q;
    }
    __syncthreads();
    {
      int f2 = tid & 7, rg = tid >> 3;           // 32 row-groups
      float s0 = 0.f, s1 = 0.f, q0 = 0.f, q1 = 0.f;
      #pragma unroll
      for (int i = 0; i < 2; i++) {
        int b = b0 + rg + 32 * i;
        float x0, x1;
        if (bf) { u32 wv = ((const u32*)a)[((size_t)n * BATCH + b) * 8 + f2]; x0 = lo2f(wv); x1 = hi2f(wv); }
        else { const float* af = (const float*)a + ((size_t)n * BATCH + b) * 16 + 2 * f2; x0 = af[0]; x1 = af[1]; }
        s0 += x0; q0 += x0 * x0; s1 += x1; q1 += x1 * x1;
      }
      S0[tid] = s0; Q0[tid] = q0; S1[tid] = s1; Q1[tid] = q1;
    }
    __syncthreads();
    if (tid < 16) {
      int f2 = tid >> 1, odd = tid & 1;
      float S = 0.f, Q = 0.f;
      #pragma unroll
      for (int rg = 0; rg < 32; rg++) {
        int ix = rg * 8 + f2;
        S += odd ? S1[ix] : S0[ix];
        Q += odd ? Q1[ix] : Q0[ix];
      }
      p[(SD + tid) * 2] = S; p[(SD + tid) * 2 + 1] = Q;
    }
    return;
  }
  int blk = blkr - 2048;   // ---- weight prep ----
  if (blk < 32) {                       // Wc1 [n][256][128] -> Wc1t [n][128][256]
    int n = blk >> 2, k0 = (blk & 3) * 64;
    for (int i = tid; i < 64 * 128; i += 256) {
      int kr = i >> 7, cc = i & 127;
      T[kr * 130 + cc] = ldbf(Wc1, ((size_t)n * 256 + k0 + kr) * 128 + cc, bf);
    }
    __syncthreads();
    for (int i = tid; i < 128 * 64; i += 256) {
      int col = i >> 6, kk = i & 63;
      Wc1t[((size_t)n * 128 + col) * 256 + k0 + kk] = T[kk * 130 + col];
    }
  } else if (blk < 40) {                // Wsa -> Wsa_t
    int n = blk - 32;
    for (int i = tid; i < 80 * 128; i += 256) {
      int kr = i >> 7, cc = i & 127;
      T[kr * 130 + cc] = ldbf(Wsa, ((size_t)n * IND + kr) * 128 + cc, bf);
    }
    __syncthreads();
    for (int i = tid; i < 128 * KP3; i += 256) {
      int col = i / KP3, k = i - col * KP3;
      Wsa_t[((size_t)n * 128 + col) * KP3 + k] = (k < IND) ? T[k * 130 + col] : (u16)0;
    }
  } else if (blk < 48) {                // Wse -> Wse_t
    int n = blk - 40;
    for (int i = tid; i < 64 * 128; i += 256) {
      int kr = i >> 7, cc = i & 127;
      T[kr * 130 + cc] = ldbf(Wse, ((size_t)n * SD + kr) * 128 + cc, bf);
    }
    __syncthreads();
    for (int i = tid; i < 128 * KPS; i += 256) {
      int col = i / KPS, k = i - col * KPS;
      Wse_t[((size_t)n * 128 + col) * KPS + k] = (k < SD) ? T[k * 130 + col] : (u16)0;
    }
  } else {                              // Wp -> Wp_t [mat][col=p*32+d][KP]
    int pm = blk - 48, p = pm / 3, mat = pm - 3 * p;
    const void* W = (mat == 0) ? Wsl : (mat == 1) ? Wk : Wv;
    for (int i = tid; i < 128 * 32; i += 256) {
      int kr = i >> 5, d = i & 31;
      T[kr * 34 + d] = ldbf(W, ((size_t)p * HID + kr) * ATT + d, bf);
    }
    __syncthreads();
    for (int i = tid; i < 32 * KP; i += 256) {
      int d = i / KP, k = i - d * KP;
      Wp_t[((size_t)mat * HID + p * ATT + d) * KP + k] = (k < HID) ? T[k * 34 + d] : (u16)0;
    }
  }
}

// ---------------- K1b: fold stats partials (coalesced) -> mst_g[8][80][2] ----------------
__global__ __launch_bounds__(256) void k_fin(const float* __restrict__ part, float* __restrict__ mst_g) {
  int n = blockIdx.x;
  int t = threadIdx.x;
  if (t < 160) {
    const float* p = part + (size_t)n * 256 * 160 + t;
    float acc = 0.f;
    #pragma unroll 8
    for (int c = 0; c < 256; c++) acc += p[(size_t)c * 160];
    float other = __shfl_xor(acc, 1);
    if ((t & 1) == 0) {
      float mean = acc * (1.f / BATCH);
      float var = other * (1.f / BATCH) - mean * mean;
      mst_g[(size_t)n * 160 + t] = mean;
      mst_g[(size_t)n * 160 + t + 1] = rsqrtf(var + EPS);
    }
  }
}

// ---------------- K2: fused encoders + projections + attention (v2, 7 barriers) ----------------
// 512 threads (8 waves), block = 16 batches x 8 agents. Wave w = agent w for all
// GEMMs; wave w = batches 2w,2w+1 for attention (interleaved rows w*16..w*16+15).
// LDS: A 34816 + Bt 34816 + wb 6144 + mst 5120 = 80896 B -> 2 blocks/CU.
__global__ __launch_bounds__(512, 4) void k_fused2(
    const void* __restrict__ s, const void* __restrict__ a,
    const u16* __restrict__ Wsa_t, const void* __restrict__ bsa,
    const u16* __restrict__ Wse_t, const void* __restrict__ bse,
    const u16* __restrict__ Wp_t, const void* __restrict__ bv_g,
    const float* __restrict__ mst_g, const int* __restrict__ flag,
    u16* __restrict__ SEo, u16* __restrict__ OT2) {
  __shared__ __align__(16) u16 A[128 * KP];    // sanb -> E -> KEYt (interleaved rows)
  __shared__ __align__(16) u16 Bt[128 * KP];   // SE -> SELt -> VALt (transposed)
  __shared__ u16 wb[128 * WBS];                // softmax weights, wave-private rows
  __shared__ float mst[NA * 160];
  bool bf = (*flag != 0);
  int tid = threadIdx.x;
  int B0 = blockIdx.x * 16;
  int w = tid >> 6, lane = tid & 63, q = lane >> 4, rl = lane & 15;
  for (int i = tid; i < NA * 160; i += 512) mst[i] = mst_g[i];
  barlg();   // B0: mst ready
  // ---- stage bn(s|a) into A: row = agent*16 + bi ----
  for (int i = tid; i < 128 * 32; i += 512) {          // s-part k 0..63
    int row = i >> 5, kp = i & 31;
    int ag = row >> 4, bi = row & 15;
    float x0, x1;
    if (bf) { u32 wv = ((const u32*)s)[((size_t)ag * BATCH + B0 + bi) * 32 + kp]; x0 = lo2f(wv); x1 = hi2f(wv); }
    else { const float* sf = (const float*)s + ((size_t)ag * BATCH + B0 + bi) * 64 + 2 * kp; x0 = sf[0]; x1 = sf[1]; }
    int k = 2 * kp;
    const float* m = &mst[ag * 160];
    u32 o = (u32)f2bf((x0 - m[k * 2]) * m[k * 2 + 1]) |
            ((u32)f2bf((x1 - m[k * 2 + 2]) * m[k * 2 + 3]) << 16);
    *(u32*)&A[row * KP + k] = o;
  }
  for (int i = tid; i < 128 * 8; i += 512) {           // a-part k 64..79
    int row = i >> 3, kp = i & 7;
    int ag = row >> 4, bi = row & 15;
    float x0, x1;
    if (bf) { u32 wv = ((const u32*)a)[((size_t)ag * BATCH + B0 + bi) * 8 + kp]; x0 = lo2f(wv); x1 = hi2f(wv); }
    else { const float* af = (const float*)a + ((size_t)ag * BATCH + B0 + bi) * 16 + 2 * kp; x0 = af[0]; x1 = af[1]; }
    int k = SD + 2 * kp;
    const float* m = &mst[ag * 160];
    u32 o = (u32)f2bf((x0 - m[k * 2]) * m[k * 2 + 1]) |
            ((u32)f2bf((x1 - m[k * 2 + 2]) * m[k * 2 + 3]) << 16);
    *(u32*)&A[row * KP + k] = o;
  }
  for (int i = tid; i < 128 * 8; i += 512) {           // zero pad k 80..95
    int row = i >> 3, c2 = i & 7;
    *(u32*)&A[row * KP + IND + 2 * c2] = 0u;
  }
  barlg();   // B1: sanb staged
  const int n = w;   // wave's agent
  const u16* WS = Wse_t + (size_t)n * HID * KPS;
  const u16* WA = Wsa_t + (size_t)n * HID * KP3;
  // ---- SE acc (K=64) and E acc (K=96), wave-private rows ----
  float4f accS[8] = {};
  #pragma unroll
  for (int kc = 0; kc < 2; kc++) {
    short8 a0 = *(const short8*)&A[(w * 16 + rl) * KP + kc * 32 + q * 8];
    #pragma unroll
    for (int nt = 0; nt < 8; nt++) {
      short8 bb = *(const short8*)(WS + (size_t)(nt * 16 + rl) * KPS + kc * 32 + q * 8);
      accS[nt] = MFMA16(a0, bb, accS[nt]);
    }
  }
  float4f accE[8] = {};
  #pragma unroll
  for (int kc = 0; kc < 3; kc++) {
    short8 a0 = *(const short8*)&A[(w * 16 + rl) * KP + kc * 32 + q * 8];
    #pragma unroll
    for (int nt = 0; nt < 8; nt++) {
      short8 bb = *(const short8*)(WA + (size_t)(nt * 16 + rl) * KP3 + kc * 32 + q * 8);
      accE[nt] = MFMA16(a0, bb, accE[nt]);
    }
  }
  barlg();   // B2: all sanb reads done
  // ---- Bt <- SE (own rows) + SEo global; A <- E (own rows); accS/accE die ----
  #pragma unroll
  for (int nt = 0; nt < 8; nt++) {
    int col = nt * 16 + rl;
    float biasS = ldin(bse, n * HID + col, bf);
    float biasE = ldin(bsa, n * HID + col, bf);
    #pragma unroll
    for (int r = 0; r < 4; r++) {
      int bi = q * 4 + r;
      u16 v = f2bf(lrelu(accS[nt][r] + biasS));
      Bt[(w * 16 + bi) * KP + col] = v;
      SEo[((size_t)n * BATCH + B0 + bi) * HID + col] = v;
      A[(w * 16 + bi) * KP + col] = f2bf(lrelu(accE[nt][r] + biasE));
    }
  }
  // ---- all-head projections, reg-accumulated (reads wave-private rows) ----
  const u16* WSL = Wp_t;                               // mat 0, [128][KP]
  const u16* WKm = Wp_t + (size_t)HID * KP;            // mat 1
  const u16* WVm = Wp_t + (size_t)2 * HID * KP;        // mat 2
  float4f aSL[4][2] = {};
  #pragma unroll
  for (int kc = 0; kc < 4; kc++) {
    short8 af = *(const short8*)&Bt[(w * 16 + rl) * KP + kc * 32 + q * 8];
    #pragma unroll
    for (int p = 0; p < HEADS; p++)
      #pragma unroll
      for (int nt = 0; nt < 2; nt++) {
        short8 bl = *(const short8*)(WSL + (size_t)(p * ATT + nt * 16 + rl) * KP + kc * 32 + q * 8);
        aSL[p][nt] = MFMA16(af, bl, aSL[p][nt]);
      }
  }
  float4f aK[4][2] = {}, aV[4][2] = {};
  #pragma unroll
  for (int kc = 0; kc < 4; kc++) {
    short8 af = *(const short8*)&A[(w * 16 + rl) * KP + kc * 32 + q * 8];
    #pragma unroll
    for (int p = 0; p < HEADS; p++)
      #pragma unroll
      for (int nt = 0; nt < 2; nt++) {
        short8 bk = *(const short8*)(WKm + (size_t)(p * ATT + nt * 16 + rl) * KP + kc * 32 + q * 8);
        aK[p][nt] = MFMA16(af, bk, aK[p][nt]);
        short8 bv8 = *(const short8*)(WVm + (size_t)(p * ATT + nt * 16 + rl) * KP + kc * 32 + q * 8);
        aV[p][nt] = MFMA16(af, bv8, aV[p][nt]);
      }
  }
  barlg();   // B3: ALL A/Bt reads done -> tiles reusable
  // ---- SELt -> Bt space, KEYt -> A space (interleaved rows) ----
  #pragma unroll
  for (int p = 0; p < HEADS; p++)
    #pragma unroll
    for (int nt = 0; nt < 2; nt++)
      #pragma unroll
      for (int r = 0; r < 4; r++) {
        int iRow = (q * 4 + r) * 8 + w, col = p * ATT + nt * 16 + rl;
        Bt[iRow * KP + col] = f2bf(aSL[p][nt][r]);
        A[iRow * KP + col] = f2bf(aK[p][nt][r]);
      }
  barlg();   // B4: SELt/KEYt visible
  short8 saf[HEADS];
  #pragma unroll
  for (int p = 0; p < HEADS; p++)
    saf[p] = lds_s8(&Bt[(w * 16 + rl) * KP + p * ATT + q * 8]);
  barlg();   // B5: SELt reads done -> Bt space free
  // ---- VALt (transposed [d][iRow]) -> Bt space ----
  #pragma unroll
  for (int p = 0; p < HEADS; p++)
    #pragma unroll
    for (int nt = 0; nt < 2; nt++) {
      int d = nt * 16 + rl;
      float bvv = ldin(bv_g, p * ATT + d, bf);
      #pragma unroll
      for (int r = 0; r < 4; r++) {
        int iRow = (q * 4 + r) * 8 + w;
        Bt[(p * ATT + d) * KP + iRow] = f2bf(lrelu(aV[p][nt][r] + bvv));
      }
    }
  barlg();   // B6: VALt visible — attention reads only stable tiles from here
  // ---- attention: 4 heads, zero barriers ----
  const float scale = 0.17677669529663687f;
  #pragma unroll
  for (int p = 0; p < HEADS; p++) {
    short8 sa = saf[p];
    short8 kb = lds_s8(&A[(w * 16 + rl) * KP + p * ATT + q * 8]);
    float4f zc = {};
    float4f c = MFMA16(sa, kb, zc);
    int nn = rl;
    #pragma unroll
    for (int r = 0; r < 4; r++) {
      int row = q * 4 + r;
      float x = c[r] * scale;
      if (row == nn) x = -1e9f;                    // self-mask (same b, i==j)
      float mx = x;
      mx = fmaxf(mx, __shfl_xor(mx, 1));
      mx = fmaxf(mx, __shfl_xor(mx, 2));
      mx = fmaxf(mx, __shfl_xor(mx, 4));
      float e = __expf(x - mx);
      float ssum = e;
      ssum += __shfl_xor(ssum, 1);
      ssum += __shfl_xor(ssum, 2);
      ssum += __shfl_xor(ssum, 4);
      float wv = e / ssum;
      if ((row >> 3) != (nn >> 3)) wv = 0.f;       // zero cross-b junk
      wb[(w * 16 + row) * WBS + nn] = f2bf(wv);    // wave-private rows
    }
    short8 aw;
    if (q < 2) aw = *(const short8*)&wb[(w * 16 + rl) * WBS + q * 8];
    else { short8 z = {}; aw = z; }
    float4f o[2] = {};
    #pragma unroll
    for (int nt = 0; nt < 2; nt++) {
      short8 bv8 = lds_s8(&Bt[(p * ATT + nt * 16 + rl) * KP + w * 16 + (q & 1) * 8]);
      o[nt] = MFMA16(aw, bv8, o[nt]);
    }
    #pragma unroll
    for (int nt = 0; nt < 2; nt++)
      #pragma unroll
      for (int r = 0; r < 4; r++) {
        int row = q * 4 + r;
        int rp = w * 16 + (row >> 3) * 8 + (row & 7);   // interleaved b*8+agent
        OT2[((size_t)blockIdx.x * 128 + rp) * HID + p * ATT + nt * 16 + rl] = f2bf(o[nt][r]);
      }
  }
}

// ---------------- K4: critic — N-split GEMM, hoisted amax/wc2f, vector gather ----------------
// LDS: Xt 34816 + wc2f 8192 + bc1f 512 + amax 512 = 44032 B
__global__ __launch_bounds__(256) void k_critic2(
    const u16* __restrict__ SEi, const u16* __restrict__ OT, const void* __restrict__ a_g,
    const u16* __restrict__ Wc1t, const void* __restrict__ bc1_g,
    const void* __restrict__ Wc2_g, const void* __restrict__ bc2_g,
    const int* __restrict__ flag, void* __restrict__ qo) {
  __shared__ __align__(16) u16 Xt[128 * KP];   // input rows; reused as ht
  __shared__ float wc2f[HID * AD];
  __shared__ float bc1f[HID];
  __shared__ int amax[128];
  bool bf = (*flag != 0);
  int tid = threadIdx.x;
  int n = blockIdx.y;
  int b0 = blockIdx.x * 128;
  int w = tid >> 6, lane = tid & 63, q = lane >> 4, rl = lane & 15;
  if (tid < HID) bc1f[tid] = ldin(bc1_g, n * HID + tid, bf);
  // ---- amax hoisted to top: coalesced 16/32B loads + shfl combine ----
  {
    int b = tid >> 1, half = tid & 1;
    float best; int bi;
    if (bf) {
      const uint4v* pa = (const uint4v*)((const u32*)a_g + ((size_t)n * BATCH + b0 + b) * 8 + half * 4);
      uint4v x = *pa;
      float v[8] = {lo2f(x[0]), hi2f(x[0]), lo2f(x[1]), hi2f(x[1]),
                    lo2f(x[2]), hi2f(x[2]), lo2f(x[3]), hi2f(x[3])};
      best = v[0]; bi = 0;
      #pragma unroll
      for (int j = 1; j < 8; j++) if (v[j] > best) { best = v[j]; bi = j; }
    } else {
      const float* pa = (const float*)a_g + ((size_t)n * BATCH + b0 + b) * 16 + half * 8;
      float4f v0 = *(const float4f*)pa, v1 = *(const float4f*)(pa + 4);
      float v[8] = {v0[0], v0[1], v0[2], v0[3], v1[0], v1[1], v1[2], v1[3]};
      best = v[0]; bi = 0;
      #pragma unroll
      for (int j = 1; j < 8; j++) if (v[j] > best) { best = v[j]; bi = j; }
    }
    float ob = __shfl_xor(best, 1);
    int obi = __shfl_xor(bi, 1);
    if (half == 0) amax[b] = (ob > best) ? (obi + 8) : bi;   // strict > = first-max
  }
  // ---- wc2f staging hoisted (latency hides under GEMM staging) ----
  for (int idx = tid; idx < HID * AD; idx += 256)
    wc2f[idx] = ldin(Wc2_g, (size_t)n * HID * AD + idx, bf);
  const u16* WT = Wc1t + (size_t)n * HID * 256;

  // ---- K=256 GEMM, N-split (wave owns 32 cols; B read once per block) ----
  float4f acc[8][2] = {};
  for (int ph = 0; ph < 2; ph++) {
    for (int idx = tid; idx < 128 * 64; idx += 256) {
      int row = idx >> 6, c = idx & 63;
      u32 wv;
      if (ph == 0) wv = ((const u32*)SEi)[((size_t)n * BATCH + b0 + row) * 64 + c];
      else         wv = ((const u32*)OT)[((size_t)(b0 + row) * NA + n) * 64 + c];
      ((u32*)&Xt[row * KP])[c] = wv;
    }
    barlg();
    #pragma unroll
    for (int kc = 0; kc < 4; kc++) {
      int ko = ph * HID + kc * 32;
      short8 bb0 = *(const short8*)(WT + (size_t)(w * 32 + rl) * 256 + ko + q * 8);
      short8 bb1 = *(const short8*)(WT + (size_t)(w * 32 + 16 + rl) * 256 + ko + q * 8);
      #pragma unroll
      for (int mt = 0; mt < 8; mt++) {
        short8 af = *(const short8*)&Xt[(mt * 16 + rl) * KP + kc * 32 + q * 8];
        acc[mt][0] = MFMA16(af, bb0, acc[mt][0]);
        acc[mt][1] = MFMA16(af, bb1, acc[mt][1]);
      }
    }
    barlg();
  }
  u16* ht = Xt;
  #pragma unroll
  for (int mt = 0; mt < 8; mt++)
    #pragma unroll
    for (int nt = 0; nt < 2; nt++)
      #pragma unroll
      for (int r = 0; r < 4; r++) {
        int row = mt * 16 + q * 4 + r, col = w * 32 + nt * 16 + rl;
        ht[row * KP + col] = f2bf(lrelu(acc[mt][nt][r] + bc1f[col]));
      }
  barlg();
  {
    int b = tid >> 1, half = tid & 1;
    int col = amax[b];
    float acq = 0.f;
    const u16* hr = &ht[b * KP + half * 64];
    const float* wz = &wc2f[(half * 64) * AD + col];
    #pragma unroll
    for (int kk = 0; kk < 8; kk++) {
      short8 hv = lds_s8(hr + kk * 8);
      #pragma unroll
      for (int j = 0; j < 8; j++)
        acq = fmaf(bf2f((u16)hv[j]), wz[(kk * 8 + j) * AD], acq);
    }
    acq += __shfl_xor(acq, 1);
    if (half == 0) {
      float v = acq + ldin(bc2_g, n * AD + col, bf);
      size_t oidx = (size_t)n * BATCH + b0 + b;
      if (bf) ((u16*)qo)[oidx] = f2bf(v);
      else    ((float*)qo)[oidx] = v;
    }
  }
}

extern "C" void kernel_launch(void* const* d_in, const int* in_sizes, int n_in,
                              void* d_out, int out_size, void* d_ws, size_t ws_size,
                              hipStream_t stream) {
  const void* s   = d_in[0];
  const void* a   = d_in[1];
  const void* Wsa = d_in[2];
  const void* bsa = d_in[3];
  const void* Wse = d_in[4];
  const void* bse = d_in[5];
  const void* Wk  = d_in[6];
  const void* Wsl = d_in[7];
  const void* Wv  = d_in[8];
  const void* bv  = d_in[9];
  const void* Wc1 = d_in[10];
  const void* bc1 = d_in[11];
  const void* Wc2 = d_in[12];
  const void* bc2 = d_in[13];

  char* ws = (char*)d_ws;
  int*   flag  = (int*)ws;
  float* part  = (float*)(ws + 1024);
  float* mst_g = (float*)(ws + 1311744);
  u16*   Wsa_t = (u16*)(ws + 1316864);
  u16*   Wse_t = (u16*)(ws + 1529856);
  u16*   Wp_t  = (u16*)(ws + 1677312);
  u16*   Wc1t  = (u16*)(ws + 1781760);
  u16*   SEb   = (u16*)(ws + 2306048);
  u16*   OT2   = (u16*)(ws + 2306048 + 1ull * 33554432ull);

  k_prep2<<<2108, 256, 0, stream>>>(s, a, Wsa, Wse, Wsl, Wk, Wv, Wc1,
                                    flag, part, Wsa_t, Wse_t, Wp_t, Wc1t);
  k_fin<<<NA, 256, 0, stream>>>(part, mst_g);
  k_fused2<<<BATCH / 16, 512, 0, stream>>>(s, a, Wsa_t, bsa, Wse_t, bse, Wp_t, bv,
                                           mst_g, flag, SEb, OT2);
  k_critic2<<<dim3(BATCH / 128, NA), 256, 0, stream>>>(SEb, OT2, a, Wc1t, bc1, Wc2, bc2, flag, d_out);
}

// Round 10
// 245.034 us; speedup vs baseline: 1.3080x; 1.3080x over previous
//
#include <hip/hip_runtime.h>

// Attention_Critic on MI355X — round 19: fix fused2's register spill + revert stats prep.
//  - k_fused3: v2's verified tile mappings, but projections SEQUENTIAL so only one
//    32-reg accumulator block is live at a time (v2 held 96 regs -> allocator gave 64
//    -> ~350MB scratch spill traffic, the round-18 regression). Order: SEL -> SELt ->
//    saf regs -> VAL -> VALt -> KEY -> KEYt. 8 barriers. Peak ~85 VGPR < 128 cap.
//  - k_prep/k_fin: reverted to the round-12 316-block version (round-13 re-grid to
//    2048 blocks was a measured +10.5us regression, never rolled back).
//  - k_critic2: byte-identical to round 16.
//
// ws layout (bytes):
//   [0,256)          int flag (1 = bf16 inputs, 0 = f32)
//   [1024,+163840)   stats partials f32 [256 blk][80][2]
//   [1311744,+5120)  mst_g f32 [8][80][2]
//   [1316864,...)    Wsa_t bf16 [8][128 col][104 k]
//   [1529856,...)    Wse_t bf16 [8][128 col][72 k]
//   [1677312,...)    Wp_t  bf16 [3 mat][128 col][136 k]  (mat 0=sel,1=key,2=val)
//   [1781760,...)    Wc1t  bf16 [8][128 col][256 k]
//   [2306048,+32M)   SE   bf16 [8][16384][128]           (agent-major)
//   [+32M,+64M)      OT2  bf16 [16384*8][128] row=b*8+agent

typedef unsigned short u16;
typedef unsigned int u32;

#define NA 8
#define BATCH 16384
#define SD 64
#define AD 16
#define IND 80
#define HID 128
#define HEADS 4
#define ATT 32
#define EPS 1e-5f
#define KP 136    // u16 stride, 128-k tiles (16B-aligned rows)
#define KP3 104   // u16 stride, 96-k tiles (Wsa_t)
#define KPS 72    // u16 stride, 64-k tiles (Wse_t)
#define WBS 24    // u16 stride, softmax weight tiles

using short8 = __attribute__((ext_vector_type(8))) short;
using float4f = __attribute__((ext_vector_type(4))) float;
using uint4v = __attribute__((ext_vector_type(4))) u32;
#define MFMA16(a, b, c) __builtin_amdgcn_mfma_f32_16x16x32_bf16((a), (b), (c), 0, 0, 0)

__device__ __forceinline__ float bf2f(u16 u) { union { u32 i; float f; } v; v.i = ((u32)u) << 16; return v.f; }
__device__ __forceinline__ float lo2f(u32 w) { union { u32 i; float f; } v; v.i = w << 16; return v.f; }
__device__ __forceinline__ float hi2f(u32 w) { union { u32 i; float f; } v; v.i = w & 0xffff0000u; return v.f; }
__device__ __forceinline__ u16 f2bf(float f) {
  union { float f; u32 i; } v; v.f = f;
  u32 x = v.i;
  x += 0x7fffu + ((x >> 16) & 1u);   // RNE
  return (u16)(x >> 16);
}
__device__ __forceinline__ float lrelu(float x) { return x > 0.f ? x : 0.01f * x; }
__device__ __forceinline__ float ldin(const void* p, size_t i, bool bf) {
  return bf ? bf2f(((const u16*)p)[i]) : ((const float*)p)[i];
}
__device__ __forceinline__ u16 ldbf(const void* p, size_t i, bool bf) {
  return bf ? ((const u16*)p)[i] : f2bf(((const float*)p)[i]);
}
__device__ __forceinline__ short8 lds_s8(const u16* p) {   // 16B LDS load, 4B-aligned ok
  union { short8 v; u32 u[4]; } t;
  const u32* q = (const u32*)p;
  t.u[0] = q[0]; t.u[1] = q[1]; t.u[2] = q[2]; t.u[3] = q[3];
  return t.v;
}
// Barrier that orders LDS only: global stores stay in flight.
__device__ __forceinline__ void barlg() {
  asm volatile("s_waitcnt lgkmcnt(0)" ::: "memory");
  __builtin_amdgcn_s_barrier();
}

// ---------------- K1: merged BN stats + weight prep (316 blocks, round-12 version) ----------------
// blocks [0,256): stats; [256,288): Wc1; [288,296): Wsa; [296,304): Wse; [304,316): Wp.
__global__ __launch_bounds__(256) void k_prep(
    const void* __restrict__ s, const void* __restrict__ a,
    const void* __restrict__ Wsa, const void* __restrict__ Wse,
    const void* __restrict__ Wsl, const void* __restrict__ Wk, const void* __restrict__ Wv,
    const void* __restrict__ Wc1,
    int* __restrict__ flag, float* __restrict__ part,
    u16* __restrict__ Wsa_t, u16* __restrict__ Wse_t, u16* __restrict__ Wp_t, u16* __restrict__ Wc1t) {
  __shared__ u16 T[80 * 130];
  __shared__ float S0[256], Q0[256], S1[256], Q1[256];
  __shared__ int cnt[2];
  int tid = threadIdx.x;
  if (tid < 2) cnt[tid] = 0;
  __syncthreads();
  {   // local dtype detection (all blocks)
    u32 wv = ((const u32*)s)[tid];
    u32 lo = wv & 0xffffu, e = (lo >> 7) & 0xffu;
    if (lo == 0u || lo == 0x8000u) atomicAdd(&cnt[1], 1);
    else if (e < 0x70u || e > 0x8fu) atomicAdd(&cnt[0], 1);
  }
  __syncthreads();
  bool bf = !(cnt[0] >= 64 || cnt[1] >= 192);
  if (blockIdx.x == 0 && tid == 0) *flag = bf ? 1 : 0;
  int blkr = blockIdx.x;
  if (blkr < 256) {   // ---- stats ----
    int blk = blkr, n = blk >> 5, c = blk & 31, b0 = c << 9;
    {
      int f2 = tid & 31, rg = tid >> 5;
      float s0 = 0.f, s1 = 0.f, q0 = 0.f, q1 = 0.f;
      for (int i = 0; i < 64; i++) {
        int b = b0 + rg + 8 * i;
        float x0, x1;
        if (bf) { u32 wv = ((const u32*)s)[((size_t)n * BATCH + b) * 32 + f2]; x0 = lo2f(wv); x1 = hi2f(wv); }
        else { const float* sf = (const float*)s + ((size_t)n * BATCH + b) * 64 + 2 * f2; x0 = sf[0]; x1 = sf[1]; }
        s0 += x0; q0 += x0 * x0; s1 += x1; q1 += x1 * x1;
      }
      S0[tid] = s0; Q0[tid] = q0; S1[tid] = s1; Q1[tid] = q1;
    }
    __syncthreads();
    if (tid < 64) {
      int f2 = tid >> 1, odd = tid & 1;
      float S = 0.f, Q = 0.f;
      for (int rg = 0; rg < 8; rg++) {
        int ix = rg * 32 + f2;
        S += odd ? S1[ix] : S0[ix];
        Q += odd ? Q1[ix] : Q0[ix];
      }
      float* p = part + ((size_t)blk * IND + tid) * 2;
      p[0] = S; p[1] = Q;
    }
    __syncthreads();
    {
      int f2 = tid & 7, rg = tid >> 3;
      float s0 = 0.f, s1 = 0.f, q0 = 0.f, q1 = 0.f;
      for (int i = 0; i < 16; i++) {
        int b = b0 + rg + 32 * i;
        float x0, x1;
        if (bf) { u32 wv = ((const u32*)a)[((size_t)n * BATCH + b) * 8 + f2]; x0 = lo2f(wv); x1 = hi2f(wv); }
        else { const float* af = (const float*)a + ((size_t)n * BATCH + b) * 16 + 2 * f2; x0 = af[0]; x1 = af[1]; }
        s0 += x0; q0 += x0 * x0; s1 += x1; q1 += x1 * x1;
      }
      S0[tid] = s0; Q0[tid] = q0; S1[tid] = s1; Q1[tid] = q1;
    }
    __syncthreads();
    if (tid < 16) {
      int f2 = tid >> 1, odd = tid & 1;
      float S = 0.f, Q = 0.f;
      for (int rg = 0; rg < 32; rg++) {
        int ix = rg * 8 + f2;
        S += odd ? S1[ix] : S0[ix];
        Q += odd ? Q1[ix] : Q0[ix];
      }
      float* p = part + ((size_t)blk * IND + SD + tid) * 2;
      p[0] = S; p[1] = Q;
    }
    return;
  }
  int blk = blkr - 256;   // ---- weight prep ----
  if (blk < 32) {                       // Wc1 [n][256][128] -> Wc1t [n][128][256]
    int n = blk >> 2, k0 = (blk & 3) * 64;
    for (int i = tid; i < 64 * 128; i += 256) {
      int kr = i >> 7, cc = i & 127;
      T[kr * 130 + cc] = ldbf(Wc1, ((size_t)n * 256 + k0 + kr) * 128 + cc, bf);
    }
    __syncthreads();
    for (int i = tid; i < 128 * 64; i += 256) {
      int col = i >> 6, kk = i & 63;
      Wc1t[((size_t)n * 128 + col) * 256 + k0 + kk] = T[kk * 130 + col];
    }
  } else if (blk < 40) {                // Wsa -> Wsa_t
    int n = blk - 32;
    for (int i = tid; i < 80 * 128; i += 256) {
      int kr = i >> 7, cc = i & 127;
      T[kr * 130 + cc] = ldbf(Wsa, ((size_t)n * IND + kr) * 128 + cc, bf);
    }
    __syncthreads();
    for (int i = tid; i < 128 * KP3; i += 256) {
      int col = i / KP3, k = i - col * KP3;
      Wsa_t[((size_t)n * 128 + col) * KP3 + k] = (k < IND) ? T[k * 130 + col] : (u16)0;
    }
  } else if (blk < 48) {                // Wse -> Wse_t
    int n = blk - 40;
    for (int i = tid; i < 64 * 128; i += 256) {
      int kr = i >> 7, cc = i & 127;
      T[kr * 130 + cc] = ldbf(Wse, ((size_t)n * SD + kr) * 128 + cc, bf);
    }
    __syncthreads();
    for (int i = tid; i < 128 * KPS; i += 256) {
      int col = i / KPS, k = i - col * KPS;
      Wse_t[((size_t)n * 128 + col) * KPS + k] = (k < SD) ? T[k * 130 + col] : (u16)0;
    }
  } else {                              // Wp -> Wp_t [mat][col=p*32+d][KP]
    int pm = blk - 48, p = pm / 3, mat = pm - 3 * p;
    const void* W = (mat == 0) ? Wsl : (mat == 1) ? Wk : Wv;
    for (int i = tid; i < 128 * 32; i += 256) {
      int kr = i >> 5, d = i & 31;
      T[kr * 34 + d] = ldbf(W, ((size_t)p * HID + kr) * ATT + d, bf);
    }
    __syncthreads();
    for (int i = tid; i < 32 * KP; i += 256) {
      int d = i / KP, k = i - d * KP;
      Wp_t[((size_t)mat * HID + p * ATT + d) * KP + k] = (k < HID) ? T[k * 34 + d] : (u16)0;
    }
  }
}

// ---------------- K1b: fold BN stats partials once -> mst_g[8][80][2] (round-12 version) ----------------
__global__ __launch_bounds__(256) void k_fin(const float* __restrict__ part, float* __restrict__ mst_g) {
  int n = blockIdx.x;
  int t = threadIdx.x;
  if (t < 160) {
    int col = t >> 1, half = t & 1;
    float S = 0.f, Q = 0.f;
    #pragma unroll
    for (int i = 0; i < 16; i++) {
      int c = half * 16 + i;
      const float* p = part + ((size_t)(n * 32 + c) * IND + col) * 2;
      S += p[0]; Q += p[1];
    }
    S += __shfl_xor(S, 1);
    Q += __shfl_xor(Q, 1);
    if (half == 0) {
      float mean = S * (1.f / BATCH);
      float var = Q * (1.f / BATCH) - mean * mean;
      mst_g[(size_t)n * IND * 2 + col * 2] = mean;
      mst_g[(size_t)n * IND * 2 + col * 2 + 1] = rsqrtf(var + EPS);
    }
  }
}

// ---------------- K2: fused encoders + projections + attention (v3: sequential, no spill) ----------------
// 512 threads (8 waves), block = 16 batches x 8 agents. Wave w = agent w for all
// GEMMs; wave w = batches 2w,2w+1 for attention (interleaved rows w*16..w*16+15).
// LDS: A 34816 + Bt 34816 + wb 6144 + mst 5120 = 80896 B -> 2 blocks/CU.
// Phases (one 32-reg projection acc live at a time; peak ~85 VGPR):
//   sanb -> {accS,accE} -> SE/E tiles -> SEL -> SELt -> saf -> VAL -> VALt -> KEY -> KEYt -> attn
__global__ __launch_bounds__(512, 4) void k_fused3(
    const void* __restrict__ s, const void* __restrict__ a,
    const u16* __restrict__ Wsa_t, const void* __restrict__ bsa,
    const u16* __restrict__ Wse_t, const void* __restrict__ bse,
    const u16* __restrict__ Wp_t, const void* __restrict__ bv_g,
    const float* __restrict__ mst_g, const int* __restrict__ flag,
    u16* __restrict__ SEo, u16* __restrict__ OT2) {
  __shared__ __align__(16) u16 A[128 * KP];    // sanb -> E -> KEYt (interleaved rows)
  __shared__ __align__(16) u16 Bt[128 * KP];   // SE -> SELt -> VALt (transposed)
  __shared__ u16 wb[128 * WBS];                // softmax weights, wave-private rows
  __shared__ float mst[NA * 160];
  bool bf = (*flag != 0);
  int tid = threadIdx.x;
  int B0 = blockIdx.x * 16;
  int w = tid >> 6, lane = tid & 63, q = lane >> 4, rl = lane & 15;
  for (int i = tid; i < NA * 160; i += 512) mst[i] = mst_g[i];
  barlg();   // B0: mst ready
  // ---- stage bn(s|a) into A: row = agent*16 + bi ----
  for (int i = tid; i < 128 * 32; i += 512) {          // s-part k 0..63
    int row = i >> 5, kp = i & 31;
    int ag = row >> 4, bi = row & 15;
    float x0, x1;
    if (bf) { u32 wv = ((const u32*)s)[((size_t)ag * BATCH + B0 + bi) * 32 + kp]; x0 = lo2f(wv); x1 = hi2f(wv); }
    else { const float* sf = (const float*)s + ((size_t)ag * BATCH + B0 + bi) * 64 + 2 * kp; x0 = sf[0]; x1 = sf[1]; }
    int k = 2 * kp;
    const float* m = &mst[ag * 160];
    u32 o = (u32)f2bf((x0 - m[k * 2]) * m[k * 2 + 1]) |
            ((u32)f2bf((x1 - m[k * 2 + 2]) * m[k * 2 + 3]) << 16);
    *(u32*)&A[row * KP + k] = o;
  }
  for (int i = tid; i < 128 * 8; i += 512) {           // a-part k 64..79
    int row = i >> 3, kp = i & 7;
    int ag = row >> 4, bi = row & 15;
    float x0, x1;
    if (bf) { u32 wv = ((const u32*)a)[((size_t)ag * BATCH + B0 + bi) * 8 + kp]; x0 = lo2f(wv); x1 = hi2f(wv); }
    else { const float* af = (const float*)a + ((size_t)ag * BATCH + B0 + bi) * 16 + 2 * kp; x0 = af[0]; x1 = af[1]; }
    int k = SD + 2 * kp;
    const float* m = &mst[ag * 160];
    u32 o = (u32)f2bf((x0 - m[k * 2]) * m[k * 2 + 1]) |
            ((u32)f2bf((x1 - m[k * 2 + 2]) * m[k * 2 + 3]) << 16);
    *(u32*)&A[row * KP + k] = o;
  }
  for (int i = tid; i < 128 * 8; i += 512) {           // zero pad k 80..95
    int row = i >> 3, c2 = i & 7;
    *(u32*)&A[row * KP + IND + 2 * c2] = 0u;
  }
  barlg();   // B1: sanb staged
  const int n = w;   // wave's agent
  const u16* WS = Wse_t + (size_t)n * HID * KPS;
  const u16* WA = Wsa_t + (size_t)n * HID * KP3;
  // ---- SE acc (K=64) and E acc (K=96), wave-private rows ----
  float4f accS[8] = {};
  #pragma unroll
  for (int kc = 0; kc < 2; kc++) {
    short8 a0 = *(const short8*)&A[(w * 16 + rl) * KP + kc * 32 + q * 8];
    #pragma unroll
    for (int nt = 0; nt < 8; nt++) {
      short8 bb = *(const short8*)(WS + (size_t)(nt * 16 + rl) * KPS + kc * 32 + q * 8);
      accS[nt] = MFMA16(a0, bb, accS[nt]);
    }
  }
  float4f accE[8] = {};
  #pragma unroll
  for (int kc = 0; kc < 3; kc++) {
    short8 a0 = *(const short8*)&A[(w * 16 + rl) * KP + kc * 32 + q * 8];
    #pragma unroll
    for (int nt = 0; nt < 8; nt++) {
      short8 bb = *(const short8*)(WA + (size_t)(nt * 16 + rl) * KP3 + kc * 32 + q * 8);
      accE[nt] = MFMA16(a0, bb, accE[nt]);
    }
  }
  barlg();   // B2: all sanb reads done
  // ---- Bt <- SE (own rows) + SEo global; A <- E (own rows); accS/accE die ----
  #pragma unroll
  for (int nt = 0; nt < 8; nt++) {
    int col = nt * 16 + rl;
    float biasS = ldin(bse, n * HID + col, bf);
    float biasE = ldin(bsa, n * HID + col, bf);
    #pragma unroll
    for (int r = 0; r < 4; r++) {
      int bi = q * 4 + r;
      u16 v = f2bf(lrelu(accS[nt][r] + biasS));
      Bt[(w * 16 + bi) * KP + col] = v;
      SEo[((size_t)n * BATCH + B0 + bi) * HID + col] = v;
      A[(w * 16 + bi) * KP + col] = f2bf(lrelu(accE[nt][r] + biasE));
    }
  }
  const u16* WSL = Wp_t;                               // mat 0, [128][KP]
  const u16* WKm = Wp_t + (size_t)HID * KP;            // mat 1
  const u16* WVm = Wp_t + (size_t)2 * HID * KP;        // mat 2
  // ---- phase SEL: acc from Bt (SE own rows); retire to SELt ----
  {
    float4f aSL[4][2] = {};
    #pragma unroll
    for (int kc = 0; kc < 4; kc++) {
      short8 af = *(const short8*)&Bt[(w * 16 + rl) * KP + kc * 32 + q * 8];
      #pragma unroll
      for (int p = 0; p < HEADS; p++)
        #pragma unroll
        for (int nt = 0; nt < 2; nt++) {
          short8 bl = *(const short8*)(WSL + (size_t)(p * ATT + nt * 16 + rl) * KP + kc * 32 + q * 8);
          aSL[p][nt] = MFMA16(af, bl, aSL[p][nt]);
        }
    }
    barlg();   // B3a: all waves' SEL reads of Bt done
    #pragma unroll
    for (int p = 0; p < HEADS; p++)
      #pragma unroll
      for (int nt = 0; nt < 2; nt++)
        #pragma unroll
        for (int r = 0; r < 4; r++) {
          int iRow = (q * 4 + r) * 8 + w, col = p * ATT + nt * 16 + rl;
          Bt[iRow * KP + col] = f2bf(aSL[p][nt][r]);
        }
  }
  barlg();   // B3b: SELt visible
  short8 saf[HEADS];
  #pragma unroll
  for (int p = 0; p < HEADS; p++)
    saf[p] = lds_s8(&Bt[(w * 16 + rl) * KP + p * ATT + q * 8]);
  barlg();   // B3c: SELt reads done -> Bt space free
  // ---- phase VAL: acc from A (E own rows); retire to VALt (transposed) in Bt ----
  {
    float4f aV[4][2] = {};
    #pragma unroll
    for (int kc = 0; kc < 4; kc++) {
      short8 af = *(const short8*)&A[(w * 16 + rl) * KP + kc * 32 + q * 8];
      #pragma unroll
      for (int p = 0; p < HEADS; p++)
        #pragma unroll
        for (int nt = 0; nt < 2; nt++) {
          short8 bv8 = *(const short8*)(WVm + (size_t)(p * ATT + nt * 16 + rl) * KP + kc * 32 + q * 8);
          aV[p][nt] = MFMA16(af, bv8, aV[p][nt]);
        }
    }
    #pragma unroll
    for (int p = 0; p < HEADS; p++)
      #pragma unroll
      for (int nt = 0; nt < 2; nt++) {
        int d = nt * 16 + rl;
        float bvv = ldin(bv_g, p * ATT + d, bf);
        #pragma unroll
        for (int r = 0; r < 4; r++) {
          int iRow = (q * 4 + r) * 8 + w;
          Bt[(p * ATT + d) * KP + iRow] = f2bf(lrelu(aV[p][nt][r] + bvv));
        }
      }
  }
  // ---- phase KEY: acc from A (E own rows); retire to KEYt in A ----
  {
    float4f aK[4][2] = {};
    #pragma unroll
    for (int kc = 0; kc < 4; kc++) {
      short8 af = *(const short8*)&A[(w * 16 + rl) * KP + kc * 32 + q * 8];
      #pragma unroll
      for (int p = 0; p < HEADS; p++)
        #pragma unroll
        for (int nt = 0; nt < 2; nt++) {
          short8 bk = *(const short8*)(WKm + (size_t)(p * ATT + nt * 16 + rl) * KP + kc * 32 + q * 8);
          aK[p][nt] = MFMA16(af, bk, aK[p][nt]);
        }
    }
    barlg();   // B4a: all waves' A reads (VAL+KEY) done -> A reusable
    #pragma unroll
    for (int p = 0; p < HEADS; p++)
      #pragma unroll
      for (int nt = 0; nt < 2; nt++)
        #pragma unroll
        for (int r = 0; r < 4; r++) {
          int iRow = (q * 4 + r) * 8 + w, col = p * ATT + nt * 16 + rl;
          A[iRow * KP + col] = f2bf(aK[p][nt][r]);
        }
  }
  barlg();   // B4b: KEYt + VALt visible — attention reads only stable tiles
  // ---- attention: 4 heads, zero barriers (v2-verified code) ----
  const float scale = 0.17677669529663687f;
  #pragma unroll
  for (int p = 0; p < HEADS; p++) {
    short8 sa = saf[p];
    short8 kb = lds_s8(&A[(w * 16 + rl) * KP + p * ATT + q * 8]);
    float4f zc = {};
    float4f c = MFMA16(sa, kb, zc);
    int nn = rl;
    #pragma unroll
    for (int r = 0; r < 4; r++) {
      int row = q * 4 + r;
      float x = c[r] * scale;
      if (row == nn) x = -1e9f;                    // self-mask (same b, i==j)
      float mx = x;
      mx = fmaxf(mx, __shfl_xor(mx, 1));
      mx = fmaxf(mx, __shfl_xor(mx, 2));
      mx = fmaxf(mx, __shfl_xor(mx, 4));
      float e = __expf(x - mx);
      float ssum = e;
      ssum += __shfl_xor(ssum, 1);
      ssum += __shfl_xor(ssum, 2);
      ssum += __shfl_xor(ssum, 4);
      float wv = e / ssum;
      if ((row >> 3) != (nn >> 3)) wv = 0.f;       // zero cross-b junk
      wb[(w * 16 + row) * WBS + nn] = f2bf(wv);    // wave-private rows
    }
    short8 aw;
    if (q < 2) aw = *(const short8*)&wb[(w * 16 + rl) * WBS + q * 8];
    else { short8 z = {}; aw = z; }
    float4f o[2] = {};
    #pragma unroll
    for (int nt = 0; nt < 2; nt++) {
      short8 bv8 = lds_s8(&Bt[(p * ATT + nt * 16 + rl) * KP + w * 16 + (q & 1) * 8]);
      o[nt] = MFMA16(aw, bv8, o[nt]);
    }
    #pragma unroll
    for (int nt = 0; nt < 2; nt++)
      #pragma unroll
      for (int r = 0; r < 4; r++) {
        int row = q * 4 + r;
        int rp = w * 16 + (row >> 3) * 8 + (row & 7);   // interleaved b*8+agent
        OT2[((size_t)blockIdx.x * 128 + rp) * HID + p * ATT + nt * 16 + rl] = f2bf(o[nt][r]);
      }
  }
}

// ---------------- K4: critic — N-split GEMM, hoisted amax/wc2f, vector gather ----------------
// LDS: Xt 34816 + wc2f 8192 + bc1f 512 + amax 512 = 44032 B
__global__ __launch_bounds__(256) void k_critic2(
    const u16* __restrict__ SEi, const u16* __restrict__ OT, const void* __restrict__ a_g,
    const u16* __restrict__ Wc1t, const void* __restrict__ bc1_g,
    const void* __restrict__ Wc2_g, const void* __restrict__ bc2_g,
    const int* __restrict__ flag, void* __restrict__ qo) {
  __shared__ __align__(16) u16 Xt[128 * KP];   // input rows; reused as ht
  __shared__ float wc2f[HID * AD];
  __shared__ float bc1f[HID];
  __shared__ int amax[128];
  bool bf = (*flag != 0);
  int tid = threadIdx.x;
  int n = blockIdx.y;
  int b0 = blockIdx.x * 128;
  int w = tid >> 6, lane = tid & 63, q = lane >> 4, rl = lane & 15;
  if (tid < HID) bc1f[tid] = ldin(bc1_g, n * HID + tid, bf);
  // ---- amax hoisted to top: coalesced 16/32B loads + shfl combine ----
  {
    int b = tid >> 1, half = tid & 1;
    float best; int bi;
    if (bf) {
      const uint4v* pa = (const uint4v*)((const u32*)a_g + ((size_t)n * BATCH + b0 + b) * 8 + half * 4);
      uint4v x = *pa;
      float v[8] = {lo2f(x[0]), hi2f(x[0]), lo2f(x[1]), hi2f(x[1]),
                    lo2f(x[2]), hi2f(x[2]), lo2f(x[3]), hi2f(x[3])};
      best = v[0]; bi = 0;
      #pragma unroll
      for (int j = 1; j < 8; j++) if (v[j] > best) { best = v[j]; bi = j; }
    } else {
      const float* pa = (const float*)a_g + ((size_t)n * BATCH + b0 + b) * 16 + half * 8;
      float4f v0 = *(const float4f*)pa, v1 = *(const float4f*)(pa + 4);
      float v[8] = {v0[0], v0[1], v0[2], v0[3], v1[0], v1[1], v1[2], v1[3]};
      best = v[0]; bi = 0;
      #pragma unroll
      for (int j = 1; j < 8; j++) if (v[j] > best) { best = v[j]; bi = j; }
    }
    float ob = __shfl_xor(best, 1);
    int obi = __shfl_xor(bi, 1);
    if (half == 0) amax[b] = (ob > best) ? (obi + 8) : bi;   // strict > = first-max
  }
  // ---- wc2f staging hoisted (latency hides under GEMM staging) ----
  for (int idx = tid; idx < HID * AD; idx += 256)
    wc2f[idx] = ldin(Wc2_g, (size_t)n * HID * AD + idx, bf);
  const u16* WT = Wc1t + (size_t)n * HID * 256;

  // ---- K=256 GEMM, N-split (wave owns 32 cols; B read once per block) ----
  float4f acc[8][2] = {};
  for (int ph = 0; ph < 2; ph++) {
    for (int idx = tid; idx < 128 * 64; idx += 256) {
      int row = idx >> 6, c = idx & 63;
      u32 wv;
      if (ph == 0) wv = ((const u32*)SEi)[((size_t)n * BATCH + b0 + row) * 64 + c];
      else         wv = ((const u32*)OT)[((size_t)(b0 + row) * NA + n) * 64 + c];
      ((u32*)&Xt[row * KP])[c] = wv;
    }
    barlg();
    #pragma unroll
    for (int kc = 0; kc < 4; kc++) {
      int ko = ph * HID + kc * 32;
      short8 bb0 = *(const short8*)(WT + (size_t)(w * 32 + rl) * 256 + ko + q * 8);
      short8 bb1 = *(const short8*)(WT + (size_t)(w * 32 + 16 + rl) * 256 + ko + q * 8);
      #pragma unroll
      for (int mt = 0; mt < 8; mt++) {
        short8 af = *(const short8*)&Xt[(mt * 16 + rl) * KP + kc * 32 + q * 8];
        acc[mt][0] = MFMA16(af, bb0, acc[mt][0]);
        acc[mt][1] = MFMA16(af, bb1, acc[mt][1]);
      }
    }
    barlg();
  }
  u16* ht = Xt;
  #pragma unroll
  for (int mt = 0; mt < 8; mt++)
    #pragma unroll
    for (int nt = 0; nt < 2; nt++)
      #pragma unroll
      for (int r = 0; r < 4; r++) {
        int row = mt * 16 + q * 4 + r, col = w * 32 + nt * 16 + rl;
        ht[row * KP + col] = f2bf(lrelu(acc[mt][nt][r] + bc1f[col]));
      }
  barlg();
  {
    int b = tid >> 1, half = tid & 1;
    int col = amax[b];
    float acq = 0.f;
    const u16* hr = &ht[b * KP + half * 64];
    const float* wz = &wc2f[(half * 64) * AD + col];
    #pragma unroll
    for (int kk = 0; kk < 8; kk++) {
      short8 hv = lds_s8(hr + kk * 8);
      #pragma unroll
      for (int j = 0; j < 8; j++)
        acq = fmaf(bf2f((u16)hv[j]), wz[(kk * 8 + j) * AD], acq);
    }
    acq += __shfl_xor(acq, 1);
    if (half == 0) {
      float v = acq + ldin(bc2_g, n * AD + col, bf);
      size_t oidx = (size_t)n * BATCH + b0 + b;
      if (bf) ((u16*)qo)[oidx] = f2bf(v);
      else    ((float*)qo)[oidx] = v;
    }
  }
}

extern "C" void kernel_launch(void* const* d_in, const int* in_sizes, int n_in,
                              void* d_out, int out_size, void* d_ws, size_t ws_size,
                              hipStream_t stream) {
  const void* s   = d_in[0];
  const void* a   = d_in[1];
  const void* Wsa = d_in[2];
  const void* bsa = d_in[3];
  const void* Wse = d_in[4];
  const void* bse = d_in[5];
  const void* Wk  = d_in[6];
  const void* Wsl = d_in[7];
  const void* Wv  = d_in[8];
  const void* bv  = d_in[9];
  const void* Wc1 = d_in[10];
  const void* bc1 = d_in[11];
  const void* Wc2 = d_in[12];
  const void* bc2 = d_in[13];

  char* ws = (char*)d_ws;
  int*   flag  = (int*)ws;
  float* part  = (float*)(ws + 1024);
  float* mst_g = (float*)(ws + 1311744);
  u16*   Wsa_t = (u16*)(ws + 1316864);
  u16*   Wse_t = (u16*)(ws + 1529856);
  u16*   Wp_t  = (u16*)(ws + 1677312);
  u16*   Wc1t  = (u16*)(ws + 1781760);
  u16*   SEb   = (u16*)(ws + 2306048);
  u16*   OT2   = (u16*)(ws + 2306048 + 1ull * 33554432ull);

  k_prep<<<316, 256, 0, stream>>>(s, a, Wsa, Wse, Wsl, Wk, Wv, Wc1,
                                  flag, part, Wsa_t, Wse_t, Wp_t, Wc1t);
  k_fin<<<NA, 256, 0, stream>>>(part, mst_g);
  k_fused3<<<BATCH / 16, 512, 0, stream>>>(s, a, Wsa_t, bsa, Wse_t, bse, Wp_t, bv,
                                           mst_g, flag, SEb, OT2);
  k_critic2<<<dim3(BATCH / 128, NA), 256, 0, stream>>>(SEb, OT2, a, Wc1t, bc1, Wc2, bc2, flag, d_out);
}

// Round 11
// 228.199 us; speedup vs baseline: 1.4045x; 1.0738x over previous
//
#include <hip/hip_runtime.h>

// Attention_Critic on MI355X — round 20: col-split the fused kernel's projections.
//  - k_fused4 (= fused3 + col-split proj): wave w computes output cols [16w,16w+16)
//    of SEL/KEY/VAL for ALL 128 rows (A-frags from the shared LDS tiles). Each lane
//    reads only its own column's B-frags -> shared proj-weight traffic per block
//    drops 830KB -> 98KB (8.5x), the same L2-feed fix that won round 12. One extra
//    barrier (9 total). Tile layouts byte-identical to fused3; attention untouched.
//  - k_prep / k_fin / k_critic2: byte-identical to round 19.
//
// ws layout (bytes):
//   [0,256)          int flag (1 = bf16 inputs, 0 = f32)
//   [1024,+163840)   stats partials f32 [256 blk][80][2]
//   [1311744,+5120)  mst_g f32 [8][80][2]
//   [1316864,...)    Wsa_t bf16 [8][128 col][104 k]
//   [1529856,...)    Wse_t bf16 [8][128 col][72 k]
//   [1677312,...)    Wp_t  bf16 [3 mat][128 col][136 k]  (mat 0=sel,1=key,2=val)
//   [1781760,...)    Wc1t  bf16 [8][128 col][256 k]
//   [2306048,+32M)   SE   bf16 [8][16384][128]           (agent-major)
//   [+32M,+64M)      OT2  bf16 [16384*8][128] row=b*8+agent

typedef unsigned short u16;
typedef unsigned int u32;

#define NA 8
#define BATCH 16384
#define SD 64
#define AD 16
#define IND 80
#define HID 128
#define HEADS 4
#define ATT 32
#define EPS 1e-5f
#define KP 136    // u16 stride, 128-k tiles (16B-aligned rows)
#define KP3 104   // u16 stride, 96-k tiles (Wsa_t)
#define KPS 72    // u16 stride, 64-k tiles (Wse_t)
#define WBS 24    // u16 stride, softmax weight tiles

using short8 = __attribute__((ext_vector_type(8))) short;
using float4f = __attribute__((ext_vector_type(4))) float;
using uint4v = __attribute__((ext_vector_type(4))) u32;
#define MFMA16(a, b, c) __builtin_amdgcn_mfma_f32_16x16x32_bf16((a), (b), (c), 0, 0, 0)

__device__ __forceinline__ float bf2f(u16 u) { union { u32 i; float f; } v; v.i = ((u32)u) << 16; return v.f; }
__device__ __forceinline__ float lo2f(u32 w) { union { u32 i; float f; } v; v.i = w << 16; return v.f; }
__device__ __forceinline__ float hi2f(u32 w) { union { u32 i; float f; } v; v.i = w & 0xffff0000u; return v.f; }
__device__ __forceinline__ u16 f2bf(float f) {
  union { float f; u32 i; } v; v.f = f;
  u32 x = v.i;
  x += 0x7fffu + ((x >> 16) & 1u);   // RNE
  return (u16)(x >> 16);
}
__device__ __forceinline__ float lrelu(float x) { return x > 0.f ? x : 0.01f * x; }
__device__ __forceinline__ float ldin(const void* p, size_t i, bool bf) {
  return bf ? bf2f(((const u16*)p)[i]) : ((const float*)p)[i];
}
__device__ __forceinline__ u16 ldbf(const void* p, size_t i, bool bf) {
  return bf ? ((const u16*)p)[i] : f2bf(((const float*)p)[i]);
}
__device__ __forceinline__ short8 lds_s8(const u16* p) {   // 16B LDS load, 4B-aligned ok
  union { short8 v; u32 u[4]; } t;
  const u32* q = (const u32*)p;
  t.u[0] = q[0]; t.u[1] = q[1]; t.u[2] = q[2]; t.u[3] = q[3];
  return t.v;
}
// Barrier that orders LDS only: global stores stay in flight.
__device__ __forceinline__ void barlg() {
  asm volatile("s_waitcnt lgkmcnt(0)" ::: "memory");
  __builtin_amdgcn_s_barrier();
}

// ---------------- K1: merged BN stats + weight prep (316 blocks) ----------------
// blocks [0,256): stats; [256,288): Wc1; [288,296): Wsa; [296,304): Wse; [304,316): Wp.
__global__ __launch_bounds__(256) void k_prep(
    const void* __restrict__ s, const void* __restrict__ a,
    const void* __restrict__ Wsa, const void* __restrict__ Wse,
    const void* __restrict__ Wsl, const void* __restrict__ Wk, const void* __restrict__ Wv,
    const void* __restrict__ Wc1,
    int* __restrict__ flag, float* __restrict__ part,
    u16* __restrict__ Wsa_t, u16* __restrict__ Wse_t, u16* __restrict__ Wp_t, u16* __restrict__ Wc1t) {
  __shared__ u16 T[80 * 130];
  __shared__ float S0[256], Q0[256], S1[256], Q1[256];
  __shared__ int cnt[2];
  int tid = threadIdx.x;
  if (tid < 2) cnt[tid] = 0;
  __syncthreads();
  {   // local dtype detection (all blocks)
    u32 wv = ((const u32*)s)[tid];
    u32 lo = wv & 0xffffu, e = (lo >> 7) & 0xffu;
    if (lo == 0u || lo == 0x8000u) atomicAdd(&cnt[1], 1);
    else if (e < 0x70u || e > 0x8fu) atomicAdd(&cnt[0], 1);
  }
  __syncthreads();
  bool bf = !(cnt[0] >= 64 || cnt[1] >= 192);
  if (blockIdx.x == 0 && tid == 0) *flag = bf ? 1 : 0;
  int blkr = blockIdx.x;
  if (blkr < 256) {   // ---- stats ----
    int blk = blkr, n = blk >> 5, c = blk & 31, b0 = c << 9;
    {
      int f2 = tid & 31, rg = tid >> 5;
      float s0 = 0.f, s1 = 0.f, q0 = 0.f, q1 = 0.f;
      for (int i = 0; i < 64; i++) {
        int b = b0 + rg + 8 * i;
        float x0, x1;
        if (bf) { u32 wv = ((const u32*)s)[((size_t)n * BATCH + b) * 32 + f2]; x0 = lo2f(wv); x1 = hi2f(wv); }
        else { const float* sf = (const float*)s + ((size_t)n * BATCH + b) * 64 + 2 * f2; x0 = sf[0]; x1 = sf[1]; }
        s0 += x0; q0 += x0 * x0; s1 += x1; q1 += x1 * x1;
      }
      S0[tid] = s0; Q0[tid] = q0; S1[tid] = s1; Q1[tid] = q1;
    }
    __syncthreads();
    if (tid < 64) {
      int f2 = tid >> 1, odd = tid & 1;
      float S = 0.f, Q = 0.f;
      for (int rg = 0; rg < 8; rg++) {
        int ix = rg * 32 + f2;
        S += odd ? S1[ix] : S0[ix];
        Q += odd ? Q1[ix] : Q0[ix];
      }
      float* p = part + ((size_t)blk * IND + tid) * 2;
      p[0] = S; p[1] = Q;
    }
    __syncthreads();
    {
      int f2 = tid & 7, rg = tid >> 3;
      float s0 = 0.f, s1 = 0.f, q0 = 0.f, q1 = 0.f;
      for (int i = 0; i < 16; i++) {
        int b = b0 + rg + 32 * i;
        float x0, x1;
        if (bf) { u32 wv = ((const u32*)a)[((size_t)n * BATCH + b) * 8 + f2]; x0 = lo2f(wv); x1 = hi2f(wv); }
        else { const float* af = (const float*)a + ((size_t)n * BATCH + b) * 16 + 2 * f2; x0 = af[0]; x1 = af[1]; }
        s0 += x0; q0 += x0 * x0; s1 += x1; q1 += x1 * x1;
      }
      S0[tid] = s0; Q0[tid] = q0; S1[tid] = s1; Q1[tid] = q1;
    }
    __syncthreads();
    if (tid < 16) {
      int f2 = tid >> 1, odd = tid & 1;
      float S = 0.f, Q = 0.f;
      for (int rg = 0; rg < 32; rg++) {
        int ix = rg * 8 + f2;
        S += odd ? S1[ix] : S0[ix];
        Q += odd ? Q1[ix] : Q0[ix];
      }
      float* p = part + ((size_t)blk * IND + SD + tid) * 2;
      p[0] = S; p[1] = Q;
    }
    return;
  }
  int blk = blkr - 256;   // ---- weight prep ----
  if (blk < 32) {                       // Wc1 [n][256][128] -> Wc1t [n][128][256]
    int n = blk >> 2, k0 = (blk & 3) * 64;
    for (int i = tid; i < 64 * 128; i += 256) {
      int kr = i >> 7, cc = i & 127;
      T[kr * 130 + cc] = ldbf(Wc1, ((size_t)n * 256 + k0 + kr) * 128 + cc, bf);
    }
    __syncthreads();
    for (int i = tid; i < 128 * 64; i += 256) {
      int col = i >> 6, kk = i & 63;
      Wc1t[((size_t)n * 128 + col) * 256 + k0 + kk] = T[kk * 130 + col];
    }
  } else if (blk < 40) {                // Wsa -> Wsa_t
    int n = blk - 32;
    for (int i = tid; i < 80 * 128; i += 256) {
      int kr = i >> 7, cc = i & 127;
      T[kr * 130 + cc] = ldbf(Wsa, ((size_t)n * IND + kr) * 128 + cc, bf);
    }
    __syncthreads();
    for (int i = tid; i < 128 * KP3; i += 256) {
      int col = i / KP3, k = i - col * KP3;
      Wsa_t[((size_t)n * 128 + col) * KP3 + k] = (k < IND) ? T[k * 130 + col] : (u16)0;
    }
  } else if (blk < 48) {                // Wse -> Wse_t
    int n = blk - 40;
    for (int i = tid; i < 64 * 128; i += 256) {
      int kr = i >> 7, cc = i & 127;
      T[kr * 130 + cc] = ldbf(Wse, ((size_t)n * SD + kr) * 128 + cc, bf);
    }
    __syncthreads();
    for (int i = tid; i < 128 * KPS; i += 256) {
      int col = i / KPS, k = i - col * KPS;
      Wse_t[((size_t)n * 128 + col) * KPS + k] = (k < SD) ? T[k * 130 + col] : (u16)0;
    }
  } else {                              // Wp -> Wp_t [mat][col=p*32+d][KP]
    int pm = blk - 48, p = pm / 3, mat = pm - 3 * p;
    const void* W = (mat == 0) ? Wsl : (mat == 1) ? Wk : Wv;
    for (int i = tid; i < 128 * 32; i += 256) {
      int kr = i >> 5, d = i & 31;
      T[kr * 34 + d] = ldbf(W, ((size_t)p * HID + kr) * ATT + d, bf);
    }
    __syncthreads();
    for (int i = tid; i < 32 * KP; i += 256) {
      int d = i / KP, k = i - d * KP;
      Wp_t[((size_t)mat * HID + p * ATT + d) * KP + k] = (k < HID) ? T[k * 34 + d] : (u16)0;
    }
  }
}

// ---------------- K1b: fold BN stats partials once -> mst_g[8][80][2] ----------------
__global__ __launch_bounds__(256) void k_fin(const float* __restrict__ part, float* __restrict__ mst_g) {
  int n = blockIdx.x;
  int t = threadIdx.x;
  if (t < 160) {
    int col = t >> 1, half = t & 1;
    float S = 0.f, Q = 0.f;
    #pragma unroll
    for (int i = 0; i < 16; i++) {
      int c = half * 16 + i;
      const float* p = part + ((size_t)(n * 32 + c) * IND + col) * 2;
      S += p[0]; Q += p[1];
    }
    S += __shfl_xor(S, 1);
    Q += __shfl_xor(Q, 1);
    if (half == 0) {
      float mean = S * (1.f / BATCH);
      float var = Q * (1.f / BATCH) - mean * mean;
      mst_g[(size_t)n * IND * 2 + col * 2] = mean;
      mst_g[(size_t)n * IND * 2 + col * 2 + 1] = rsqrtf(var + EPS);
    }
  }
}

// ---------------- K2: fused encoders + col-split projections + attention ----------------
// 512 threads (8 waves), block = 16 batches x 8 agents. Wave w = agent w for the
// SE/E GEMMs (per-agent weights); wave w = output cols [16w,16w+16) for the three
// projection GEMMs (shared weights, read once per LANE-column: 8.5x less traffic);
// wave w = batches 2w,2w+1 for attention.
// LDS: A 34816 + Bt 34816 + wb 6144 + mst 5120 = 80896 B -> 2 blocks/CU. 9 barriers.
__global__ __launch_bounds__(512, 4) void k_fused4(
    const void* __restrict__ s, const void* __restrict__ a,
    const u16* __restrict__ Wsa_t, const void* __restrict__ bsa,
    const u16* __restrict__ Wse_t, const void* __restrict__ bse,
    const u16* __restrict__ Wp_t, const void* __restrict__ bv_g,
    const float* __restrict__ mst_g, const int* __restrict__ flag,
    u16* __restrict__ SEo, u16* __restrict__ OT2) {
  __shared__ __align__(16) u16 A[128 * KP];    // sanb -> E -> KEYt (interleaved rows)
  __shared__ __align__(16) u16 Bt[128 * KP];   // SE -> SELt -> VALt (transposed)
  __shared__ u16 wb[128 * WBS];                // softmax weights, wave-private rows
  __shared__ float mst[NA * 160];
  bool bf = (*flag != 0);
  int tid = threadIdx.x;
  int B0 = blockIdx.x * 16;
  int w = tid >> 6, lane = tid & 63, q = lane >> 4, rl = lane & 15;
  for (int i = tid; i < NA * 160; i += 512) mst[i] = mst_g[i];
  barlg();   // B0: mst ready
  // ---- stage bn(s|a) into A: row = agent*16 + bi ----
  for (int i = tid; i < 128 * 32; i += 512) {          // s-part k 0..63
    int row = i >> 5, kp = i & 31;
    int ag = row >> 4, bi = row & 15;
    float x0, x1;
    if (bf) { u32 wv = ((const u32*)s)[((size_t)ag * BATCH + B0 + bi) * 32 + kp]; x0 = lo2f(wv); x1 = hi2f(wv); }
    else { const float* sf = (const float*)s + ((size_t)ag * BATCH + B0 + bi) * 64 + 2 * kp; x0 = sf[0]; x1 = sf[1]; }
    int k = 2 * kp;
    const float* m = &mst[ag * 160];
    u32 o = (u32)f2bf((x0 - m[k * 2]) * m[k * 2 + 1]) |
            ((u32)f2bf((x1 - m[k * 2 + 2]) * m[k * 2 + 3]) << 16);
    *(u32*)&A[row * KP + k] = o;
  }
  for (int i = tid; i < 128 * 8; i += 512) {           // a-part k 64..79
    int row = i >> 3, kp = i & 7;
    int ag = row >> 4, bi = row & 15;
    float x0, x1;
    if (bf) { u32 wv = ((const u32*)a)[((size_t)ag * BATCH + B0 + bi) * 8 + kp]; x0 = lo2f(wv); x1 = hi2f(wv); }
    else { const float* af = (const float*)a + ((size_t)ag * BATCH + B0 + bi) * 16 + 2 * kp; x0 = af[0]; x1 = af[1]; }
    int k = SD + 2 * kp;
    const float* m = &mst[ag * 160];
    u32 o = (u32)f2bf((x0 - m[k * 2]) * m[k * 2 + 1]) |
            ((u32)f2bf((x1 - m[k * 2 + 2]) * m[k * 2 + 3]) << 16);
    *(u32*)&A[row * KP + k] = o;
  }
  for (int i = tid; i < 128 * 8; i += 512) {           // zero pad k 80..95
    int row = i >> 3, c2 = i & 7;
    *(u32*)&A[row * KP + IND + 2 * c2] = 0u;
  }
  barlg();   // B1: sanb staged
  const int n = w;   // wave's agent (SE/E phases)
  const u16* WS = Wse_t + (size_t)n * HID * KPS;
  const u16* WA = Wsa_t + (size_t)n * HID * KP3;
  // ---- SE acc (K=64) and E acc (K=96), wave-private rows ----
  float4f accS[8] = {};
  #pragma unroll
  for (int kc = 0; kc < 2; kc++) {
    short8 a0 = *(const short8*)&A[(w * 16 + rl) * KP + kc * 32 + q * 8];
    #pragma unroll
    for (int nt = 0; nt < 8; nt++) {
      short8 bb = *(const short8*)(WS + (size_t)(nt * 16 + rl) * KPS + kc * 32 + q * 8);
      accS[nt] = MFMA16(a0, bb, accS[nt]);
    }
  }
  float4f accE[8] = {};
  #pragma unroll
  for (int kc = 0; kc < 3; kc++) {
    short8 a0 = *(const short8*)&A[(w * 16 + rl) * KP + kc * 32 + q * 8];
    #pragma unroll
    for (int nt = 0; nt < 8; nt++) {
      short8 bb = *(const short8*)(WA + (size_t)(nt * 16 + rl) * KP3 + kc * 32 + q * 8);
      accE[nt] = MFMA16(a0, bb, accE[nt]);
    }
  }
  barlg();   // B2: all sanb reads done
  // ---- Bt <- SE (own rows) + SEo global; A <- E (own rows); accS/accE die ----
  #pragma unroll
  for (int nt = 0; nt < 8; nt++) {
    int col = nt * 16 + rl;
    float biasS = ldin(bse, n * HID + col, bf);
    float biasE = ldin(bsa, n * HID + col, bf);
    #pragma unroll
    for (int r = 0; r < 4; r++) {
      int bi = q * 4 + r;
      u16 v = f2bf(lrelu(accS[nt][r] + biasS));
      Bt[(w * 16 + bi) * KP + col] = v;
      SEo[((size_t)n * BATCH + B0 + bi) * HID + col] = v;
      A[(w * 16 + bi) * KP + col] = f2bf(lrelu(accE[nt][r] + biasE));
    }
  }
  barlg();   // B3: SE (Bt) and E (A) tiles fully visible to all waves
  const u16* WSL = Wp_t;                               // mat 0, [128 col][KP]
  const u16* WKm = Wp_t + (size_t)HID * KP;            // mat 1
  const u16* WVm = Wp_t + (size_t)2 * HID * KP;        // mat 2
  const int myc = w * 16 + rl;                         // this lane's output column
  // ---- phase SEL (col-split): cols [16w,16w+16) x all 128 rows; B-frag per LANE ----
  {
    float4f aSL[8] = {};
    #pragma unroll
    for (int kc = 0; kc < 4; kc++) {
      short8 bl = *(const short8*)(WSL + (size_t)myc * KP + kc * 32 + q * 8);
      #pragma unroll
      for (int mt = 0; mt < 8; mt++) {
        short8 af = lds_s8(&Bt[(mt * 16 + rl) * KP + kc * 32 + q * 8]);
        aSL[mt] = MFMA16(af, bl, aSL[mt]);
      }
    }
    barlg();   // B4: all Bt (SE) reads done
    #pragma unroll
    for (int mt = 0; mt < 8; mt++)
      #pragma unroll
      for (int r = 0; r < 4; r++) {
        int iRow = (q * 4 + r) * 8 + mt;   // bi*8 + agent
        Bt[iRow * KP + myc] = f2bf(aSL[mt][r]);
      }
  }
  barlg();   // B5: SELt visible
  short8 saf[HEADS];
  #pragma unroll
  for (int p = 0; p < HEADS; p++)
    saf[p] = lds_s8(&Bt[(w * 16 + rl) * KP + p * ATT + q * 8]);
  barlg();   // B6: SELt reads done -> Bt space free
  // ---- phase VAL (col-split): retire transposed into Bt ----
  {
    float4f aV[8] = {};
    #pragma unroll
    for (int kc = 0; kc < 4; kc++) {
      short8 bv8 = *(const short8*)(WVm + (size_t)myc * KP + kc * 32 + q * 8);
      #pragma unroll
      for (int mt = 0; mt < 8; mt++) {
        short8 af = lds_s8(&A[(mt * 16 + rl) * KP + kc * 32 + q * 8]);
        aV[mt] = MFMA16(af, bv8, aV[mt]);
      }
    }
    float bvv = ldin(bv_g, myc, bf);
    #pragma unroll
    for (int mt = 0; mt < 8; mt++)
      #pragma unroll
      for (int r = 0; r < 4; r++) {
        int iRow = (q * 4 + r) * 8 + mt;
        Bt[myc * KP + iRow] = f2bf(lrelu(aV[mt][r] + bvv));   // VALt [d][iRow]
      }
  }
  // ---- phase KEY (col-split): retire into A ----
  {
    float4f aK[8] = {};
    #pragma unroll
    for (int kc = 0; kc < 4; kc++) {
      short8 bk = *(const short8*)(WKm + (size_t)myc * KP + kc * 32 + q * 8);
      #pragma unroll
      for (int mt = 0; mt < 8; mt++) {
        short8 af = lds_s8(&A[(mt * 16 + rl) * KP + kc * 32 + q * 8]);
        aK[mt] = MFMA16(af, bk, aK[mt]);
      }
    }
    barlg();   // B7: all A (E) reads done (VAL+KEY) -> A reusable
    #pragma unroll
    for (int mt = 0; mt < 8; mt++)
      #pragma unroll
      for (int r = 0; r < 4; r++) {
        int iRow = (q * 4 + r) * 8 + mt;
        A[iRow * KP + myc] = f2bf(aK[mt][r]);
      }
  }
  barlg();   // B8: KEYt + VALt visible — attention reads only stable tiles
  // ---- attention: 4 heads, zero barriers (verified code) ----
  const float scale = 0.17677669529663687f;
  #pragma unroll
  for (int p = 0; p < HEADS; p++) {
    short8 sa = saf[p];
    short8 kb = lds_s8(&A[(w * 16 + rl) * KP + p * ATT + q * 8]);
    float4f zc = {};
    float4f c = MFMA16(sa, kb, zc);
    int nn = rl;
    #pragma unroll
    for (int r = 0; r < 4; r++) {
      int row = q * 4 + r;
      float x = c[r] * scale;
      if (row == nn) x = -1e9f;                    // self-mask (same b, i==j)
      float mx = x;
      mx = fmaxf(mx, __shfl_xor(mx, 1));
      mx = fmaxf(mx, __shfl_xor(mx, 2));
      mx = fmaxf(mx, __shfl_xor(mx, 4));
      float e = __expf(x - mx);
      float ssum = e;
      ssum += __shfl_xor(ssum, 1);
      ssum += __shfl_xor(ssum, 2);
      ssum += __shfl_xor(ssum, 4);
      float wv = e / ssum;
      if ((row >> 3) != (nn >> 3)) wv = 0.f;       // zero cross-b junk
      wb[(w * 16 + row) * WBS + nn] = f2bf(wv);    // wave-private rows
    }
    short8 aw;
    if (q < 2) aw = *(const short8*)&wb[(w * 16 + rl) * WBS + q * 8];
    else { short8 z = {}; aw = z; }
    float4f o[2] = {};
    #pragma unroll
    for (int nt = 0; nt < 2; nt++) {
      short8 bv8 = lds_s8(&Bt[(p * ATT + nt * 16 + rl) * KP + w * 16 + (q & 1) * 8]);
      o[nt] = MFMA16(aw, bv8, o[nt]);
    }
    #pragma unroll
    for (int nt = 0; nt < 2; nt++)
      #pragma unroll
      for (int r = 0; r < 4; r++) {
        int row = q * 4 + r;
        int rp = w * 16 + (row >> 3) * 8 + (row & 7);   // interleaved b*8+agent
        OT2[((size_t)blockIdx.x * 128 + rp) * HID + p * ATT + nt * 16 + rl] = f2bf(o[nt][r]);
      }
  }
}

// ---------------- K4: critic — N-split GEMM, hoisted amax/wc2f, vector gather ----------------
// LDS: Xt 34816 + wc2f 8192 + bc1f 512 + amax 512 = 44032 B
__global__ __launch_bounds__(256) void k_critic2(
    const u16* __restrict__ SEi, const u16* __restrict__ OT, const void* __restrict__ a_g,
    const u16* __restrict__ Wc1t, const void* __restrict__ bc1_g,
    const void* __restrict__ Wc2_g, const void* __restrict__ bc2_g,
    const int* __restrict__ flag, void* __restrict__ qo) {
  __shared__ __align__(16) u16 Xt[128 * KP];   // input rows; reused as ht
  __shared__ float wc2f[HID * AD];
  __shared__ float bc1f[HID];
  __shared__ int amax[128];
  bool bf = (*flag != 0);
  int tid = threadIdx.x;
  int n = blockIdx.y;
  int b0 = blockIdx.x * 128;
  int w = tid >> 6, lane = tid & 63, q = lane >> 4, rl = lane & 15;
  if (tid < HID) bc1f[tid] = ldin(bc1_g, n * HID + tid, bf);
  // ---- amax hoisted to top: coalesced 16/32B loads + shfl combine ----
  {
    int b = tid >> 1, half = tid & 1;
    float best; int bi;
    if (bf) {
      const uint4v* pa = (const uint4v*)((const u32*)a_g + ((size_t)n * BATCH + b0 + b) * 8 + half * 4);
      uint4v x = *pa;
      float v[8] = {lo2f(x[0]), hi2f(x[0]), lo2f(x[1]), hi2f(x[1]),
                    lo2f(x[2]), hi2f(x[2]), lo2f(x[3]), hi2f(x[3])};
      best = v[0]; bi = 0;
      #pragma unroll
      for (int j = 1; j < 8; j++) if (v[j] > best) { best = v[j]; bi = j; }
    } else {
      const float* pa = (const float*)a_g + ((size_t)n * BATCH + b0 + b) * 16 + half * 8;
      float4f v0 = *(const float4f*)pa, v1 = *(const float4f*)(pa + 4);
      float v[8] = {v0[0], v0[1], v0[2], v0[3], v1[0], v1[1], v1[2], v1[3]};
      best = v[0]; bi = 0;
      #pragma unroll
      for (int j = 1; j < 8; j++) if (v[j] > best) { best = v[j]; bi = j; }
    }
    float ob = __shfl_xor(best, 1);
    int obi = __shfl_xor(bi, 1);
    if (half == 0) amax[b] = (ob > best) ? (obi + 8) : bi;   // strict > = first-max
  }
  // ---- wc2f staging hoisted (latency hides under GEMM staging) ----
  for (int idx = tid; idx < HID * AD; idx += 256)
    wc2f[idx] = ldin(Wc2_g, (size_t)n * HID * AD + idx, bf);
  const u16* WT = Wc1t + (size_t)n * HID * 256;

  // ---- K=256 GEMM, N-split (wave owns 32 cols; B read once per block) ----
  float4f acc[8][2] = {};
  for (int ph = 0; ph < 2; ph++) {
    for (int idx = tid; idx < 128 * 64; idx += 256) {
      int row = idx >> 6, c = idx & 63;
      u32 wv;
      if (ph == 0) wv = ((const u32*)SEi)[((size_t)n * BATCH + b0 + row) * 64 + c];
      else         wv = ((const u32*)OT)[((size_t)(b0 + row) * NA + n) * 64 + c];
      ((u32*)&Xt[row * KP])[c] = wv;
    }
    barlg();
    #pragma unroll
    for (int kc = 0; kc < 4; kc++) {
      int ko = ph * HID + kc * 32;
      short8 bb0 = *(const short8*)(WT + (size_t)(w * 32 + rl) * 256 + ko + q * 8);
      short8 bb1 = *(const short8*)(WT + (size_t)(w * 32 + 16 + rl) * 256 + ko + q * 8);
      #pragma unroll
      for (int mt = 0; mt < 8; mt++) {
        short8 af = *(const short8*)&Xt[(mt * 16 + rl) * KP + kc * 32 + q * 8];
        acc[mt][0] = MFMA16(af, bb0, acc[mt][0]);
        acc[mt][1] = MFMA16(af, bb1, acc[mt][1]);
      }
    }
    barlg();
  }
  u16* ht = Xt;
  #pragma unroll
  for (int mt = 0; mt < 8; mt++)
    #pragma unroll
    for (int nt = 0; nt < 2; nt++)
      #pragma unroll
      for (int r = 0; r < 4; r++) {
        int row = mt * 16 + q * 4 + r, col = w * 32 + nt * 16 + rl;
        ht[row * KP + col] = f2bf(lrelu(acc[mt][nt][r] + bc1f[col]));
      }
  barlg();
  {
    int b = tid >> 1, half = tid & 1;
    int col = amax[b];
    float acq = 0.f;
    const u16* hr = &ht[b * KP + half * 64];
    const float* wz = &wc2f[(half * 64) * AD + col];
    #pragma unroll
    for (int kk = 0; kk < 8; kk++) {
      short8 hv = lds_s8(hr + kk * 8);
      #pragma unroll
      for (int j = 0; j < 8; j++)
        acq = fmaf(bf2f((u16)hv[j]), wz[(kk * 8 + j) * AD], acq);
    }
    acq += __shfl_xor(acq, 1);
    if (half == 0) {
      float v = acq + ldin(bc2_g, n * AD + col, bf);
      size_t oidx = (size_t)n * BATCH + b0 + b;
      if (bf) ((u16*)qo)[oidx] = f2bf(v);
      else    ((float*)qo)[oidx] = v;
    }
  }
}

extern "C" void kernel_launch(void* const* d_in, const int* in_sizes, int n_in,
                              void* d_out, int out_size, void* d_ws, size_t ws_size,
                              hipStream_t stream) {
  const void* s   = d_in[0];
  const void* a   = d_in[1];
  const void* Wsa = d_in[2];
  const void* bsa = d_in[3];
  const void* Wse = d_in[4];
  const void* bse = d_in[5];
  const void* Wk  = d_in[6];
  const void* Wsl = d_in[7];
  const void* Wv  = d_in[8];
  const void* bv  = d_in[9];
  const void* Wc1 = d_in[10];
  const void* bc1 = d_in[11];
  const void* Wc2 = d_in[12];
  const void* bc2 = d_in[13];

  char* ws = (char*)d_ws;
  int*   flag  = (int*)ws;
  float* part  = (float*)(ws + 1024);
  float* mst_g = (float*)(ws + 1311744);
  u16*   Wsa_t = (u16*)(ws + 1316864);
  u16*   Wse_t = (u16*)(ws + 1529856);
  u16*   Wp_t  = (u16*)(ws + 1677312);
  u16*   Wc1t  = (u16*)(ws + 1781760);
  u16*   SEb   = (u16*)(ws + 2306048);
  u16*   OT2   = (u16*)(ws + 2306048 + 1ull * 33554432ull);

  k_prep<<<316, 256, 0, stream>>>(s, a, Wsa, Wse, Wsl, Wk, Wv, Wc1,
                                  flag, part, Wsa_t, Wse_t, Wp_t, Wc1t);
  k_fin<<<NA, 256, 0, stream>>>(part, mst_g);
  k_fused4<<<BATCH / 16, 512, 0, stream>>>(s, a, Wsa_t, bsa, Wse_t, bse, Wp_t, bv,
                                           mst_g, flag, SEb, OT2);
  k_critic2<<<dim3(BATCH / 128, NA), 256, 0, stream>>>(SEb, OT2, a, Wc1t, bc1, Wc2, bc2, flag, d_out);
}

// Round 12
// 213.805 us; speedup vs baseline: 1.4990x; 1.0673x over previous
//
#include <hip/hip_runtime.h>

// Attention_Critic on MI355X — round 21: de-spill fused4 + fix VALt bank conflict.
//  - k_fused5 (= fused4 + two local fixes):
//    (a) SEL/KEY accumulators packed to bf16-pair u32s BEFORE their retire
//        barriers (same f2bf values, earlier) -> cross-barrier live regs halved
//        (32 f32 -> 16 u32) -> the ~54MB/dispatch scratch spill (FETCH 41MB,
//        WRITE 109MB in round 20) should vanish.
//    (b) VALt row stride 136 -> 134 u16 (67 dwords == 3 mod 32, coprime) ->
//        transposed VALt write + attention PV read go 8-way -> conflict-free.
//  - k_prep / k_fin / k_critic2: byte-identical to round 20.
//
// ws layout (bytes):
//   [0,256)          int flag (1 = bf16 inputs, 0 = f32)
//   [1024,+163840)   stats partials f32 [256 blk][80][2]
//   [1311744,+5120)  mst_g f32 [8][80][2]
//   [1316864,...)    Wsa_t bf16 [8][128 col][104 k]
//   [1529856,...)    Wse_t bf16 [8][128 col][72 k]
//   [1677312,...)    Wp_t  bf16 [3 mat][128 col][136 k]  (mat 0=sel,1=key,2=val)
//   [1781760,...)    Wc1t  bf16 [8][128 col][256 k]
//   [2306048,+32M)   SE   bf16 [8][16384][128]           (agent-major)
//   [+32M,+64M)      OT2  bf16 [16384*8][128] row=b*8+agent

typedef unsigned short u16;
typedef unsigned int u32;

#define NA 8
#define BATCH 16384
#define SD 64
#define AD 16
#define IND 80
#define HID 128
#define HEADS 4
#define ATT 32
#define EPS 1e-5f
#define KP 136    // u16 stride, 128-k tiles (16B-aligned rows)
#define KP3 104   // u16 stride, 96-k tiles (Wsa_t)
#define KPS 72    // u16 stride, 64-k tiles (Wse_t)
#define VTS3 134  // u16 stride, VALt [128 d][128 iRow] (67 dwords == 3 mod 32: conflict-free)
#define WBS 24    // u16 stride, softmax weight tiles

using short8 = __attribute__((ext_vector_type(8))) short;
using float4f = __attribute__((ext_vector_type(4))) float;
using uint4v = __attribute__((ext_vector_type(4))) u32;
#define MFMA16(a, b, c) __builtin_amdgcn_mfma_f32_16x16x32_bf16((a), (b), (c), 0, 0, 0)

__device__ __forceinline__ float bf2f(u16 u) { union { u32 i; float f; } v; v.i = ((u32)u) << 16; return v.f; }
__device__ __forceinline__ float lo2f(u32 w) { union { u32 i; float f; } v; v.i = w << 16; return v.f; }
__device__ __forceinline__ float hi2f(u32 w) { union { u32 i; float f; } v; v.i = w & 0xffff0000u; return v.f; }
__device__ __forceinline__ u16 f2bf(float f) {
  union { float f; u32 i; } v; v.f = f;
  u32 x = v.i;
  x += 0x7fffu + ((x >> 16) & 1u);   // RNE
  return (u16)(x >> 16);
}
__device__ __forceinline__ float lrelu(float x) { return x > 0.f ? x : 0.01f * x; }
__device__ __forceinline__ float ldin(const void* p, size_t i, bool bf) {
  return bf ? bf2f(((const u16*)p)[i]) : ((const float*)p)[i];
}
__device__ __forceinline__ u16 ldbf(const void* p, size_t i, bool bf) {
  return bf ? ((const u16*)p)[i] : f2bf(((const float*)p)[i]);
}
__device__ __forceinline__ short8 lds_s8(const u16* p) {   // 16B LDS load, 4B-aligned ok
  union { short8 v; u32 u[4]; } t;
  const u32* q = (const u32*)p;
  t.u[0] = q[0]; t.u[1] = q[1]; t.u[2] = q[2]; t.u[3] = q[3];
  return t.v;
}
// Barrier that orders LDS only: global stores stay in flight.
__device__ __forceinline__ void barlg() {
  asm volatile("s_waitcnt lgkmcnt(0)" ::: "memory");
  __builtin_amdgcn_s_barrier();
}

// ---------------- K1: merged BN stats + weight prep (316 blocks) ----------------
// blocks [0,256): stats; [256,288): Wc1; [288,296): Wsa; [296,304): Wse; [304,316): Wp.
__global__ __launch_bounds__(256) void k_prep(
    const void* __restrict__ s, const void* __restrict__ a,
    const void* __restrict__ Wsa, const void* __restrict__ Wse,
    const void* __restrict__ Wsl, const void* __restrict__ Wk, const void* __restrict__ Wv,
    const void* __restrict__ Wc1,
    int* __restrict__ flag, float* __restrict__ part,
    u16* __restrict__ Wsa_t, u16* __restrict__ Wse_t, u16* __restrict__ Wp_t, u16* __restrict__ Wc1t) {
  __shared__ u16 T[80 * 130];
  __shared__ float S0[256], Q0[256], S1[256], Q1[256];
  __shared__ int cnt[2];
  int tid = threadIdx.x;
  if (tid < 2) cnt[tid] = 0;
  __syncthreads();
  {   // local dtype detection (all blocks)
    u32 wv = ((const u32*)s)[tid];
    u32 lo = wv & 0xffffu, e = (lo >> 7) & 0xffu;
    if (lo == 0u || lo == 0x8000u) atomicAdd(&cnt[1], 1);
    else if (e < 0x70u || e > 0x8fu) atomicAdd(&cnt[0], 1);
  }
  __syncthreads();
  bool bf = !(cnt[0] >= 64 || cnt[1] >= 192);
  if (blockIdx.x == 0 && tid == 0) *flag = bf ? 1 : 0;
  int blkr = blockIdx.x;
  if (blkr < 256) {   // ---- stats ----
    int blk = blkr, n = blk >> 5, c = blk & 31, b0 = c << 9;
    {
      int f2 = tid & 31, rg = tid >> 5;
      float s0 = 0.f, s1 = 0.f, q0 = 0.f, q1 = 0.f;
      for (int i = 0; i < 64; i++) {
        int b = b0 + rg + 8 * i;
        float x0, x1;
        if (bf) { u32 wv = ((const u32*)s)[((size_t)n * BATCH + b) * 32 + f2]; x0 = lo2f(wv); x1 = hi2f(wv); }
        else { const float* sf = (const float*)s + ((size_t)n * BATCH + b) * 64 + 2 * f2; x0 = sf[0]; x1 = sf[1]; }
        s0 += x0; q0 += x0 * x0; s1 += x1; q1 += x1 * x1;
      }
      S0[tid] = s0; Q0[tid] = q0; S1[tid] = s1; Q1[tid] = q1;
    }
    __syncthreads();
    if (tid < 64) {
      int f2 = tid >> 1, odd = tid & 1;
      float S = 0.f, Q = 0.f;
      for (int rg = 0; rg < 8; rg++) {
        int ix = rg * 32 + f2;
        S += odd ? S1[ix] : S0[ix];
        Q += odd ? Q1[ix] : Q0[ix];
      }
      float* p = part + ((size_t)blk * IND + tid) * 2;
      p[0] = S; p[1] = Q;
    }
    __syncthreads();
    {
      int f2 = tid & 7, rg = tid >> 3;
      float s0 = 0.f, s1 = 0.f, q0 = 0.f, q1 = 0.f;
      for (int i = 0; i < 16; i++) {
        int b = b0 + rg + 32 * i;
        float x0, x1;
        if (bf) { u32 wv = ((const u32*)a)[((size_t)n * BATCH + b) * 8 + f2]; x0 = lo2f(wv); x1 = hi2f(wv); }
        else { const float* af = (const float*)a + ((size_t)n * BATCH + b) * 16 + 2 * f2; x0 = af[0]; x1 = af[1]; }
        s0 += x0; q0 += x0 * x0; s1 += x1; q1 += x1 * x1;
      }
      S0[tid] = s0; Q0[tid] = q0; S1[tid] = s1; Q1[tid] = q1;
    }
    __syncthreads();
    if (tid < 16) {
      int f2 = tid >> 1, odd = tid & 1;
      float S = 0.f, Q = 0.f;
      for (int rg = 0; rg < 32; rg++) {
        int ix = rg * 8 + f2;
        S += odd ? S1[ix] : S0[ix];
        Q += odd ? Q1[ix] : Q0[ix];
      }
      float* p = part + ((size_t)blk * IND + SD + tid) * 2;
      p[0] = S; p[1] = Q;
    }
    return;
  }
  int blk = blkr - 256;   // ---- weight prep ----
  if (blk < 32) {                       // Wc1 [n][256][128] -> Wc1t [n][128][256]
    int n = blk >> 2, k0 = (blk & 3) * 64;
    for (int i = tid; i < 64 * 128; i += 256) {
      int kr = i >> 7, cc = i & 127;
      T[kr * 130 + cc] = ldbf(Wc1, ((size_t)n * 256 + k0 + kr) * 128 + cc, bf);
    }
    __syncthreads();
    for (int i = tid; i < 128 * 64; i += 256) {
      int col = i >> 6, kk = i & 63;
      Wc1t[((size_t)n * 128 + col) * 256 + k0 + kk] = T[kk * 130 + col];
    }
  } else if (blk < 40) {                // Wsa -> Wsa_t
    int n = blk - 32;
    for (int i = tid; i < 80 * 128; i += 256) {
      int kr = i >> 7, cc = i & 127;
      T[kr * 130 + cc] = ldbf(Wsa, ((size_t)n * IND + kr) * 128 + cc, bf);
    }
    __syncthreads();
    for (int i = tid; i < 128 * KP3; i += 256) {
      int col = i / KP3, k = i - col * KP3;
      Wsa_t[((size_t)n * 128 + col) * KP3 + k] = (k < IND) ? T[k * 130 + col] : (u16)0;
    }
  } else if (blk < 48) {                // Wse -> Wse_t
    int n = blk - 40;
    for (int i = tid; i < 64 * 128; i += 256) {
      int kr = i >> 7, cc = i & 127;
      T[kr * 130 + cc] = ldbf(Wse, ((size_t)n * SD + kr) * 128 + cc, bf);
    }
    __syncthreads();
    for (int i = tid; i < 128 * KPS; i += 256) {
      int col = i / KPS, k = i - col * KPS;
      Wse_t[((size_t)n * 128 + col) * KPS + k] = (k < SD) ? T[k * 130 + col] : (u16)0;
    }
  } else {                              // Wp -> Wp_t [mat][col=p*32+d][KP]
    int pm = blk - 48, p = pm / 3, mat = pm - 3 * p;
    const void* W = (mat == 0) ? Wsl : (mat == 1) ? Wk : Wv;
    for (int i = tid; i < 128 * 32; i += 256) {
      int kr = i >> 5, d = i & 31;
      T[kr * 34 + d] = ldbf(W, ((size_t)p * HID + kr) * ATT + d, bf);
    }
    __syncthreads();
    for (int i = tid; i < 32 * KP; i += 256) {
      int d = i / KP, k = i - d * KP;
      Wp_t[((size_t)mat * HID + p * ATT + d) * KP + k] = (k < HID) ? T[k * 34 + d] : (u16)0;
    }
  }
}

// ---------------- K1b: fold BN stats partials once -> mst_g[8][80][2] ----------------
__global__ __launch_bounds__(256) void k_fin(const float* __restrict__ part, float* __restrict__ mst_g) {
  int n = blockIdx.x;
  int t = threadIdx.x;
  if (t < 160) {
    int col = t >> 1, half = t & 1;
    float S = 0.f, Q = 0.f;
    #pragma unroll
    for (int i = 0; i < 16; i++) {
      int c = half * 16 + i;
      const float* p = part + ((size_t)(n * 32 + c) * IND + col) * 2;
      S += p[0]; Q += p[1];
    }
    S += __shfl_xor(S, 1);
    Q += __shfl_xor(Q, 1);
    if (half == 0) {
      float mean = S * (1.f / BATCH);
      float var = Q * (1.f / BATCH) - mean * mean;
      mst_g[(size_t)n * IND * 2 + col * 2] = mean;
      mst_g[(size_t)n * IND * 2 + col * 2 + 1] = rsqrtf(var + EPS);
    }
  }
}

// ---------------- K2: fused encoders + col-split projections + attention ----------------
// 512 threads (8 waves), block = 16 batches x 8 agents. Wave w = agent w for the
// SE/E GEMMs; wave w = output cols [16w,16w+16) for the projections; wave w =
// batches 2w,2w+1 for attention.
// LDS: A 34816 + Bt 34816 + wb 6144 + mst 5120 = 80896 B -> 2 blocks/CU. 9 barriers.
// SEL/KEY results packed to bf16-pair u32s BEFORE their barriers (16 live regs,
// not 32) to stay inside the 64-VGPR grant; VALt at stride 134 (conflict-free).
__global__ __launch_bounds__(512, 4) void k_fused5(
    const void* __restrict__ s, const void* __restrict__ a,
    const u16* __restrict__ Wsa_t, const void* __restrict__ bsa,
    const u16* __restrict__ Wse_t, const void* __restrict__ bse,
    const u16* __restrict__ Wp_t, const void* __restrict__ bv_g,
    const float* __restrict__ mst_g, const int* __restrict__ flag,
    u16* __restrict__ SEo, u16* __restrict__ OT2) {
  __shared__ __align__(16) u16 A[128 * KP];    // sanb -> E -> KEYt (interleaved rows)
  __shared__ __align__(16) u16 Bt[128 * KP];   // SE -> SELt -> VALt (stride VTS3)
  __shared__ u16 wb[128 * WBS];                // softmax weights, wave-private rows
  __shared__ float mst[NA * 160];
  bool bf = (*flag != 0);
  int tid = threadIdx.x;
  int B0 = blockIdx.x * 16;
  int w = tid >> 6, lane = tid & 63, q = lane >> 4, rl = lane & 15;
  for (int i = tid; i < NA * 160; i += 512) mst[i] = mst_g[i];
  barlg();   // B0: mst ready
  // ---- stage bn(s|a) into A: row = agent*16 + bi ----
  for (int i = tid; i < 128 * 32; i += 512) {          // s-part k 0..63
    int row = i >> 5, kp = i & 31;
    int ag = row >> 4, bi = row & 15;
    float x0, x1;
    if (bf) { u32 wv = ((const u32*)s)[((size_t)ag * BATCH + B0 + bi) * 32 + kp]; x0 = lo2f(wv); x1 = hi2f(wv); }
    else { const float* sf = (const float*)s + ((size_t)ag * BATCH + B0 + bi) * 64 + 2 * kp; x0 = sf[0]; x1 = sf[1]; }
    int k = 2 * kp;
    const float* m = &mst[ag * 160];
    u32 o = (u32)f2bf((x0 - m[k * 2]) * m[k * 2 + 1]) |
            ((u32)f2bf((x1 - m[k * 2 + 2]) * m[k * 2 + 3]) << 16);
    *(u32*)&A[row * KP + k] = o;
  }
  for (int i = tid; i < 128 * 8; i += 512) {           // a-part k 64..79
    int row = i >> 3, kp = i & 7;
    int ag = row >> 4, bi = row & 15;
    float x0, x1;
    if (bf) { u32 wv = ((const u32*)a)[((size_t)ag * BATCH + B0 + bi) * 8 + kp]; x0 = lo2f(wv); x1 = hi2f(wv); }
    else { const float* af = (const float*)a + ((size_t)ag * BATCH + B0 + bi) * 16 + 2 * kp; x0 = af[0]; x1 = af[1]; }
    int k = SD + 2 * kp;
    const float* m = &mst[ag * 160];
    u32 o = (u32)f2bf((x0 - m[k * 2]) * m[k * 2 + 1]) |
            ((u32)f2bf((x1 - m[k * 2 + 2]) * m[k * 2 + 3]) << 16);
    *(u32*)&A[row * KP + k] = o;
  }
  for (int i = tid; i < 128 * 8; i += 512) {           // zero pad k 80..95
    int row = i >> 3, c2 = i & 7;
    *(u32*)&A[row * KP + IND + 2 * c2] = 0u;
  }
  barlg();   // B1: sanb staged
  const int n = w;   // wave's agent (SE/E phases)
  const u16* WS = Wse_t + (size_t)n * HID * KPS;
  const u16* WA = Wsa_t + (size_t)n * HID * KP3;
  // ---- SE acc (K=64) and E acc (K=96), wave-private rows ----
  float4f accS[8] = {};
  #pragma unroll
  for (int kc = 0; kc < 2; kc++) {
    short8 a0 = *(const short8*)&A[(w * 16 + rl) * KP + kc * 32 + q * 8];
    #pragma unroll
    for (int nt = 0; nt < 8; nt++) {
      short8 bb = *(const short8*)(WS + (size_t)(nt * 16 + rl) * KPS + kc * 32 + q * 8);
      accS[nt] = MFMA16(a0, bb, accS[nt]);
    }
  }
  float4f accE[8] = {};
  #pragma unroll
  for (int kc = 0; kc < 3; kc++) {
    short8 a0 = *(const short8*)&A[(w * 16 + rl) * KP + kc * 32 + q * 8];
    #pragma unroll
    for (int nt = 0; nt < 8; nt++) {
      short8 bb = *(const short8*)(WA + (size_t)(nt * 16 + rl) * KP3 + kc * 32 + q * 8);
      accE[nt] = MFMA16(a0, bb, accE[nt]);
    }
  }
  barlg();   // B2: all sanb reads done
  // ---- Bt <- SE (own rows) + SEo global; A <- E (own rows); accS/accE die ----
  #pragma unroll
  for (int nt = 0; nt < 8; nt++) {
    int col = nt * 16 + rl;
    float biasS = ldin(bse, n * HID + col, bf);
    float biasE = ldin(bsa, n * HID + col, bf);
    #pragma unroll
    for (int r = 0; r < 4; r++) {
      int bi = q * 4 + r;
      u16 v = f2bf(lrelu(accS[nt][r] + biasS));
      Bt[(w * 16 + bi) * KP + col] = v;
      SEo[((size_t)n * BATCH + B0 + bi) * HID + col] = v;
      A[(w * 16 + bi) * KP + col] = f2bf(lrelu(accE[nt][r] + biasE));
    }
  }
  barlg();   // B3: SE (Bt) and E (A) tiles fully visible to all waves
  const u16* WSL = Wp_t;                               // mat 0, [128 col][KP]
  const u16* WKm = Wp_t + (size_t)HID * KP;            // mat 1
  const u16* WVm = Wp_t + (size_t)2 * HID * KP;        // mat 2
  const int myc = w * 16 + rl;                         // this lane's output column
  // ---- phase SEL (col-split): pack to bf16 pairs BEFORE barrier ----
  {
    float4f aSL[8] = {};
    #pragma unroll
    for (int kc = 0; kc < 4; kc++) {
      short8 bl = *(const short8*)(WSL + (size_t)myc * KP + kc * 32 + q * 8);
      #pragma unroll
      for (int mt = 0; mt < 8; mt++) {
        short8 af = lds_s8(&Bt[(mt * 16 + rl) * KP + kc * 32 + q * 8]);
        aSL[mt] = MFMA16(af, bl, aSL[mt]);
      }
    }
    u32 pk[16];
    #pragma unroll
    for (int mt = 0; mt < 8; mt++) {
      pk[2 * mt]     = (u32)f2bf(aSL[mt][0]) | ((u32)f2bf(aSL[mt][1]) << 16);
      pk[2 * mt + 1] = (u32)f2bf(aSL[mt][2]) | ((u32)f2bf(aSL[mt][3]) << 16);
    }
    barlg();   // B4: all Bt (SE) reads done  (only pk[16] live across)
    #pragma unroll
    for (int mt = 0; mt < 8; mt++)
      #pragma unroll
      for (int r = 0; r < 4; r++) {
        int iRow = (q * 4 + r) * 8 + mt;   // bi*8 + agent
        Bt[iRow * KP + myc] = (u16)(pk[2 * mt + (r >> 1)] >> ((r & 1) * 16));
      }
  }
  barlg();   // B5: SELt visible
  short8 saf[HEADS];
  #pragma unroll
  for (int p = 0; p < HEADS; p++)
    saf[p] = lds_s8(&Bt[(w * 16 + rl) * KP + p * ATT + q * 8]);
  barlg();   // B6: SELt reads done -> Bt space free
  // ---- phase VAL (col-split): retire transposed into Bt at stride VTS3 ----
  {
    float4f aV[8] = {};
    #pragma unroll
    for (int kc = 0; kc < 4; kc++) {
      short8 bv8 = *(const short8*)(WVm + (size_t)myc * KP + kc * 32 + q * 8);
      #pragma unroll
      for (int mt = 0; mt < 8; mt++) {
        short8 af = lds_s8(&A[(mt * 16 + rl) * KP + kc * 32 + q * 8]);
        aV[mt] = MFMA16(af, bv8, aV[mt]);
      }
    }
    float bvv = ldin(bv_g, myc, bf);
    #pragma unroll
    for (int mt = 0; mt < 8; mt++)
      #pragma unroll
      for (int r = 0; r < 4; r++) {
        int iRow = (q * 4 + r) * 8 + mt;
        Bt[myc * VTS3 + iRow] = f2bf(lrelu(aV[mt][r] + bvv));   // VALt [d][iRow]
      }
  }
  // ---- phase KEY (col-split): pack BEFORE barrier, retire into A ----
  {
    float4f aK[8] = {};
    #pragma unroll
    for (int kc = 0; kc < 4; kc++) {
      short8 bk = *(const short8*)(WKm + (size_t)myc * KP + kc * 32 + q * 8);
      #pragma unroll
      for (int mt = 0; mt < 8; mt++) {
        short8 af = lds_s8(&A[(mt * 16 + rl) * KP + kc * 32 + q * 8]);
        aK[mt] = MFMA16(af, bk, aK[mt]);
      }
    }
    u32 pk[16];
    #pragma unroll
    for (int mt = 0; mt < 8; mt++) {
      pk[2 * mt]     = (u32)f2bf(aK[mt][0]) | ((u32)f2bf(aK[mt][1]) << 16);
      pk[2 * mt + 1] = (u32)f2bf(aK[mt][2]) | ((u32)f2bf(aK[mt][3]) << 16);
    }
    barlg();   // B7: all A (E) reads done (VAL+KEY) -> A reusable
    #pragma unroll
    for (int mt = 0; mt < 8; mt++)
      #pragma unroll
      for (int r = 0; r < 4; r++) {
        int iRow = (q * 4 + r) * 8 + mt;
        A[iRow * KP + myc] = (u16)(pk[2 * mt + (r >> 1)] >> ((r & 1) * 16));
      }
  }
  barlg();   // B8: KEYt + VALt visible — attention reads only stable tiles
  // ---- attention: 4 heads, zero barriers (verified code) ----
  const float scale = 0.17677669529663687f;
  #pragma unroll
  for (int p = 0; p < HEADS; p++) {
    short8 sa = saf[p];
    short8 kb = lds_s8(&A[(w * 16 + rl) * KP + p * ATT + q * 8]);
    float4f zc = {};
    float4f c = MFMA16(sa, kb, zc);
    int nn = rl;
    #pragma unroll
    for (int r = 0; r < 4; r++) {
      int row = q * 4 + r;
      float x = c[r] * scale;
      if (row == nn) x = -1e9f;                    // self-mask (same b, i==j)
      float mx = x;
      mx = fmaxf(mx, __shfl_xor(mx, 1));
      mx = fmaxf(mx, __shfl_xor(mx, 2));
      mx = fmaxf(mx, __shfl_xor(mx, 4));
      float e = __expf(x - mx);
      float ssum = e;
      ssum += __shfl_xor(ssum, 1);
      ssum += __shfl_xor(ssum, 2);
      ssum += __shfl_xor(ssum, 4);
      float wv = e / ssum;
      if ((row >> 3) != (nn >> 3)) wv = 0.f;       // zero cross-b junk
      wb[(w * 16 + row) * WBS + nn] = f2bf(wv);    // wave-private rows
    }
    short8 aw;
    if (q < 2) aw = *(const short8*)&wb[(w * 16 + rl) * WBS + q * 8];
    else { short8 z = {}; aw = z; }
    float4f o[2] = {};
    #pragma unroll
    for (int nt = 0; nt < 2; nt++) {
      short8 bv8 = lds_s8(&Bt[(p * ATT + nt * 16 + rl) * VTS3 + w * 16 + (q & 1) * 8]);
      o[nt] = MFMA16(aw, bv8, o[nt]);
    }
    #pragma unroll
    for (int nt = 0; nt < 2; nt++)
      #pragma unroll
      for (int r = 0; r < 4; r++) {
        int row = q * 4 + r;
        int rp = w * 16 + (row >> 3) * 8 + (row & 7);   // interleaved b*8+agent
        OT2[((size_t)blockIdx.x * 128 + rp) * HID + p * ATT + nt * 16 + rl] = f2bf(o[nt][r]);
      }
  }
}

// ---------------- K4: critic — N-split GEMM, hoisted amax/wc2f, vector gather ----------------
// LDS: Xt 34816 + wc2f 8192 + bc1f 512 + amax 512 = 44032 B
__global__ __launch_bounds__(256) void k_critic2(
    const u16* __restrict__ SEi, const u16* __restrict__ OT, const void* __restrict__ a_g,
    const u16* __restrict__ Wc1t, const void* __restrict__ bc1_g,
    const void* __restrict__ Wc2_g, const void* __restrict__ bc2_g,
    const int* __restrict__ flag, void* __restrict__ qo) {
  __shared__ __align__(16) u16 Xt[128 * KP];   // input rows; reused as ht
  __shared__ float wc2f[HID * AD];
  __shared__ float bc1f[HID];
  __shared__ int amax[128];
  bool bf = (*flag != 0);
  int tid = threadIdx.x;
  int n = blockIdx.y;
  int b0 = blockIdx.x * 128;
  int w = tid >> 6, lane = tid & 63, q = lane >> 4, rl = lane & 15;
  if (tid < HID) bc1f[tid] = ldin(bc1_g, n * HID + tid, bf);
  // ---- amax hoisted to top: coalesced 16/32B loads + shfl combine ----
  {
    int b = tid >> 1, half = tid & 1;
    float best; int bi;
    if (bf) {
      const uint4v* pa = (const uint4v*)((const u32*)a_g + ((size_t)n * BATCH + b0 + b) * 8 + half * 4);
      uint4v x = *pa;
      float v[8] = {lo2f(x[0]), hi2f(x[0]), lo2f(x[1]), hi2f(x[1]),
                    lo2f(x[2]), hi2f(x[2]), lo2f(x[3]), hi2f(x[3])};
      best = v[0]; bi = 0;
      #pragma unroll
      for (int j = 1; j < 8; j++) if (v[j] > best) { best = v[j]; bi = j; }
    } else {
      const float* pa = (const float*)a_g + ((size_t)n * BATCH + b0 + b) * 16 + half * 8;
      float4f v0 = *(const float4f*)pa, v1 = *(const float4f*)(pa + 4);
      float v[8] = {v0[0], v0[1], v0[2], v0[3], v1[0], v1[1], v1[2], v1[3]};
      best = v[0]; bi = 0;
      #pragma unroll
      for (int j = 1; j < 8; j++) if (v[j] > best) { best = v[j]; bi = j; }
    }
    float ob = __shfl_xor(best, 1);
    int obi = __shfl_xor(bi, 1);
    if (half == 0) amax[b] = (ob > best) ? (obi + 8) : bi;   // strict > = first-max
  }
  // ---- wc2f staging hoisted (latency hides under GEMM staging) ----
  for (int idx = tid; idx < HID * AD; idx += 256)
    wc2f[idx] = ldin(Wc2_g, (size_t)n * HID * AD + idx, bf);
  const u16* WT = Wc1t + (size_t)n * HID * 256;

  // ---- K=256 GEMM, N-split (wave owns 32 cols; B read once per block) ----
  float4f acc[8][2] = {};
  for (int ph = 0; ph < 2; ph++) {
    for (int idx = tid; idx < 128 * 64; idx += 256) {
      int row = idx >> 6, c = idx & 63;
      u32 wv;
      if (ph == 0) wv = ((const u32*)SEi)[((size_t)n * BATCH + b0 + row) * 64 + c];
      else         wv = ((const u32*)OT)[((size_t)(b0 + row) * NA + n) * 64 + c];
      ((u32*)&Xt[row * KP])[c] = wv;
    }
    barlg();
    #pragma unroll
    for (int kc = 0; kc < 4; kc++) {
      int ko = ph * HID + kc * 32;
      short8 bb0 = *(const short8*)(WT + (size_t)(w * 32 + rl) * 256 + ko + q * 8);
      short8 bb1 = *(const short8*)(WT + (size_t)(w * 32 + 16 + rl) * 256 + ko + q * 8);
      #pragma unroll
      for (int mt = 0; mt < 8; mt++) {
        short8 af = *(const short8*)&Xt[(mt * 16 + rl) * KP + kc * 32 + q * 8];
        acc[mt][0] = MFMA16(af, bb0, acc[mt][0]);
        acc[mt][1] = MFMA16(af, bb1, acc[mt][1]);
      }
    }
    barlg();
  }
  u16* ht = Xt;
  #pragma unroll
  for (int mt = 0; mt < 8; mt++)
    #pragma unroll
    for (int nt = 0; nt < 2; nt++)
      #pragma unroll
      for (int r = 0; r < 4; r++) {
        int row = mt * 16 + q * 4 + r, col = w * 32 + nt * 16 + rl;
        ht[row * KP + col] = f2bf(lrelu(acc[mt][nt][r] + bc1f[col]));
      }
  barlg();
  {
    int b = tid >> 1, half = tid & 1;
    int col = amax[b];
    float acq = 0.f;
    const u16* hr = &ht[b * KP + half * 64];
    const float* wz = &wc2f[(half * 64) * AD + col];
    #pragma unroll
    for (int kk = 0; kk < 8; kk++) {
      short8 hv = lds_s8(hr + kk * 8);
      #pragma unroll
      for (int j = 0; j < 8; j++)
        acq = fmaf(bf2f((u16)hv[j]), wz[(kk * 8 + j) * AD], acq);
    }
    acq += __shfl_xor(acq, 1);
    if (half == 0) {
      float v = acq + ldin(bc2_g, n * AD + col, bf);
      size_t oidx = (size_t)n * BATCH + b0 + b;
      if (bf) ((u16*)qo)[oidx] = f2bf(v);
      else    ((float*)qo)[oidx] = v;
    }
  }
}

extern "C" void kernel_launch(void* const* d_in, const int* in_sizes, int n_in,
                              void* d_out, int out_size, void* d_ws, size_t ws_size,
                              hipStream_t stream) {
  const void* s   = d_in[0];
  const void* a   = d_in[1];
  const void* Wsa = d_in[2];
  const void* bsa = d_in[3];
  const void* Wse = d_in[4];
  const void* bse = d_in[5];
  const void* Wk  = d_in[6];
  const void* Wsl = d_in[7];
  const void* Wv  = d_in[8];
  const void* bv  = d_in[9];
  const void* Wc1 = d_in[10];
  const void* bc1 = d_in[11];
  const void* Wc2 = d_in[12];
  const void* bc2 = d_in[13];

  char* ws = (char*)d_ws;
  int*   flag  = (int*)ws;
  float* part  = (float*)(ws + 1024);
  float* mst_g = (float*)(ws + 1311744);
  u16*   Wsa_t = (u16*)(ws + 1316864);
  u16*   Wse_t = (u16*)(ws + 1529856);
  u16*   Wp_t  = (u16*)(ws + 1677312);
  u16*   Wc1t  = (u16*)(ws + 1781760);
  u16*   SEb   = (u16*)(ws + 2306048);
  u16*   OT2   = (u16*)(ws + 2306048 + 1ull * 33554432ull);

  k_prep<<<316, 256, 0, stream>>>(s, a, Wsa, Wse, Wsl, Wk, Wv, Wc1,
                                  flag, part, Wsa_t, Wse_t, Wp_t, Wc1t);
  k_fin<<<NA, 256, 0, stream>>>(part, mst_g);
  k_fused5<<<BATCH / 16, 512, 0, stream>>>(s, a, Wsa_t, bsa, Wse_t, bse, Wp_t, bv,
                                           mst_g, flag, SEb, OT2);
  k_critic2<<<dim3(BATCH / 128, NA), 256, 0, stream>>>(SEb, OT2, a, Wc1t, bc1, Wc2, bc2, flag, d_out);
}

// Round 13
// 211.468 us; speedup vs baseline: 1.5156x; 1.0111x over previous
//
#include <hip/hip_runtime.h>

// Attention_Critic on MI355X — round 22: MLP unrolls + SEL-weight prefetch.
//  - k_prep: stats loops unrolled (8-deep MLP; was ~1 outstanding load/thread,
//    64 serial HBM latencies). Weight-prep loops unroll 4.
//  - k_fused6 (= fused5 + WSL prefetch): the barlg "memory" clobber pins each
//    phase's weight loads behind the preceding barrier; WSL frags (16 VGPR) are
//    now issued BEFORE B3 so they're in flight across it. WVm/WKm not hoisted
//    (saf[16] live there; 64-VGPR grant — spill risk).
//  - k_critic2: staging loops unrolled.
//  All numerics byte-identical to round 21 (absmax must stay 0.0078125).
//
// ws layout (bytes):
//   [0,256)          int flag (1 = bf16 inputs, 0 = f32)
//   [1024,+163840)   stats partials f32 [256 blk][80][2]
//   [1311744,+5120)  mst_g f32 [8][80][2]
//   [1316864,...)    Wsa_t bf16 [8][128 col][104 k]
//   [1529856,...)    Wse_t bf16 [8][128 col][72 k]
//   [1677312,...)    Wp_t  bf16 [3 mat][128 col][136 k]  (mat 0=sel,1=key,2=val)
//   [1781760,...)    Wc1t  bf16 [8][128 col][256 k]
//   [2306048,+32M)   SE   bf16 [8][16384][128]           (agent-major)
//   [+32M,+64M)      OT2  bf16 [16384*8][128] row=b*8+agent

typedef unsigned short u16;
typedef unsigned int u32;

#define NA 8
#define BATCH 16384
#define SD 64
#define AD 16
#define IND 80
#define HID 128
#define HEADS 4
#define ATT 32
#define EPS 1e-5f
#define KP 136    // u16 stride, 128-k tiles (16B-aligned rows)
#define KP3 104   // u16 stride, 96-k tiles (Wsa_t)
#define KPS 72    // u16 stride, 64-k tiles (Wse_t)
#define VTS3 134  // u16 stride, VALt [128 d][128 iRow] (67 dwords == 3 mod 32: conflict-free)
#define WBS 24    // u16 stride, softmax weight tiles

using short8 = __attribute__((ext_vector_type(8))) short;
using float4f = __attribute__((ext_vector_type(4))) float;
using uint4v = __attribute__((ext_vector_type(4))) u32;
#define MFMA16(a, b, c) __builtin_amdgcn_mfma_f32_16x16x32_bf16((a), (b), (c), 0, 0, 0)

__device__ __forceinline__ float bf2f(u16 u) { union { u32 i; float f; } v; v.i = ((u32)u) << 16; return v.f; }
__device__ __forceinline__ float lo2f(u32 w) { union { u32 i; float f; } v; v.i = w << 16; return v.f; }
__device__ __forceinline__ float hi2f(u32 w) { union { u32 i; float f; } v; v.i = w & 0xffff0000u; return v.f; }
__device__ __forceinline__ u16 f2bf(float f) {
  union { float f; u32 i; } v; v.f = f;
  u32 x = v.i;
  x += 0x7fffu + ((x >> 16) & 1u);   // RNE
  return (u16)(x >> 16);
}
__device__ __forceinline__ float lrelu(float x) { return x > 0.f ? x : 0.01f * x; }
__device__ __forceinline__ float ldin(const void* p, size_t i, bool bf) {
  return bf ? bf2f(((const u16*)p)[i]) : ((const float*)p)[i];
}
__device__ __forceinline__ u16 ldbf(const void* p, size_t i, bool bf) {
  return bf ? ((const u16*)p)[i] : f2bf(((const float*)p)[i]);
}
__device__ __forceinline__ short8 lds_s8(const u16* p) {   // 16B LDS load, 4B-aligned ok
  union { short8 v; u32 u[4]; } t;
  const u32* q = (const u32*)p;
  t.u[0] = q[0]; t.u[1] = q[1]; t.u[2] = q[2]; t.u[3] = q[3];
  return t.v;
}
// Barrier that orders LDS only: global stores stay in flight.
__device__ __forceinline__ void barlg() {
  asm volatile("s_waitcnt lgkmcnt(0)" ::: "memory");
  __builtin_amdgcn_s_barrier();
}

// ---------------- K1: merged BN stats + weight prep (316 blocks) ----------------
// blocks [0,256): stats; [256,288): Wc1; [288,296): Wsa; [296,304): Wse; [304,316): Wp.
__global__ __launch_bounds__(256) void k_prep(
    const void* __restrict__ s, const void* __restrict__ a,
    const void* __restrict__ Wsa, const void* __restrict__ Wse,
    const void* __restrict__ Wsl, const void* __restrict__ Wk, const void* __restrict__ Wv,
    const void* __restrict__ Wc1,
    int* __restrict__ flag, float* __restrict__ part,
    u16* __restrict__ Wsa_t, u16* __restrict__ Wse_t, u16* __restrict__ Wp_t, u16* __restrict__ Wc1t) {
  __shared__ u16 T[80 * 130];
  __shared__ float S0[256], Q0[256], S1[256], Q1[256];
  __shared__ int cnt[2];
  int tid = threadIdx.x;
  if (tid < 2) cnt[tid] = 0;
  __syncthreads();
  {   // local dtype detection (all blocks)
    u32 wv = ((const u32*)s)[tid];
    u32 lo = wv & 0xffffu, e = (lo >> 7) & 0xffu;
    if (lo == 0u || lo == 0x8000u) atomicAdd(&cnt[1], 1);
    else if (e < 0x70u || e > 0x8fu) atomicAdd(&cnt[0], 1);
  }
  __syncthreads();
  bool bf = !(cnt[0] >= 64 || cnt[1] >= 192);
  if (blockIdx.x == 0 && tid == 0) *flag = bf ? 1 : 0;
  int blkr = blockIdx.x;
  if (blkr < 256) {   // ---- stats ----
    int blk = blkr, n = blk >> 5, c = blk & 31, b0 = c << 9;
    {
      int f2 = tid & 31, rg = tid >> 5;
      float s0 = 0.f, s1 = 0.f, q0 = 0.f, q1 = 0.f;
      #pragma unroll 8
      for (int i = 0; i < 64; i++) {
        int b = b0 + rg + 8 * i;
        float x0, x1;
        if (bf) { u32 wv = ((const u32*)s)[((size_t)n * BATCH + b) * 32 + f2]; x0 = lo2f(wv); x1 = hi2f(wv); }
        else { const float* sf = (const float*)s + ((size_t)n * BATCH + b) * 64 + 2 * f2; x0 = sf[0]; x1 = sf[1]; }
        s0 += x0; q0 += x0 * x0; s1 += x1; q1 += x1 * x1;
      }
      S0[tid] = s0; Q0[tid] = q0; S1[tid] = s1; Q1[tid] = q1;
    }
    __syncthreads();
    if (tid < 64) {
      int f2 = tid >> 1, odd = tid & 1;
      float S = 0.f, Q = 0.f;
      #pragma unroll
      for (int rg = 0; rg < 8; rg++) {
        int ix = rg * 32 + f2;
        S += odd ? S1[ix] : S0[ix];
        Q += odd ? Q1[ix] : Q0[ix];
      }
      float* p = part + ((size_t)blk * IND + tid) * 2;
      p[0] = S; p[1] = Q;
    }
    __syncthreads();
    {
      int f2 = tid & 7, rg = tid >> 3;
      float s0 = 0.f, s1 = 0.f, q0 = 0.f, q1 = 0.f;
      #pragma unroll 8
      for (int i = 0; i < 16; i++) {
        int b = b0 + rg + 32 * i;
        float x0, x1;
        if (bf) { u32 wv = ((const u32*)a)[((size_t)n * BATCH + b) * 8 + f2]; x0 = lo2f(wv); x1 = hi2f(wv); }
        else { const float* af = (const float*)a + ((size_t)n * BATCH + b) * 16 + 2 * f2; x0 = af[0]; x1 = af[1]; }
        s0 += x0; q0 += x0 * x0; s1 += x1; q1 += x1 * x1;
      }
      S0[tid] = s0; Q0[tid] = q0; S1[tid] = s1; Q1[tid] = q1;
    }
    __syncthreads();
    if (tid < 16) {
      int f2 = tid >> 1, odd = tid & 1;
      float S = 0.f, Q = 0.f;
      #pragma unroll
      for (int rg = 0; rg < 32; rg++) {
        int ix = rg * 8 + f2;
        S += odd ? S1[ix] : S0[ix];
        Q += odd ? Q1[ix] : Q0[ix];
      }
      float* p = part + ((size_t)blk * IND + SD + tid) * 2;
      p[0] = S; p[1] = Q;
    }
    return;
  }
  int blk = blkr - 256;   // ---- weight prep ----
  if (blk < 32) {                       // Wc1 [n][256][128] -> Wc1t [n][128][256]
    int n = blk >> 2, k0 = (blk & 3) * 64;
    #pragma unroll 4
    for (int i = tid; i < 64 * 128; i += 256) {
      int kr = i >> 7, cc = i & 127;
      T[kr * 130 + cc] = ldbf(Wc1, ((size_t)n * 256 + k0 + kr) * 128 + cc, bf);
    }
    __syncthreads();
    #pragma unroll 4
    for (int i = tid; i < 128 * 64; i += 256) {
      int col = i >> 6, kk = i & 63;
      Wc1t[((size_t)n * 128 + col) * 256 + k0 + kk] = T[kk * 130 + col];
    }
  } else if (blk < 40) {                // Wsa -> Wsa_t
    int n = blk - 32;
    #pragma unroll 4
    for (int i = tid; i < 80 * 128; i += 256) {
      int kr = i >> 7, cc = i & 127;
      T[kr * 130 + cc] = ldbf(Wsa, ((size_t)n * IND + kr) * 128 + cc, bf);
    }
    __syncthreads();
    #pragma unroll 4
    for (int i = tid; i < 128 * KP3; i += 256) {
      int col = i / KP3, k = i - col * KP3;
      Wsa_t[((size_t)n * 128 + col) * KP3 + k] = (k < IND) ? T[k * 130 + col] : (u16)0;
    }
  } else if (blk < 48) {                // Wse -> Wse_t
    int n = blk - 40;
    #pragma unroll 4
    for (int i = tid; i < 64 * 128; i += 256) {
      int kr = i >> 7, cc = i & 127;
      T[kr * 130 + cc] = ldbf(Wse, ((size_t)n * SD + kr) * 128 + cc, bf);
    }
    __syncthreads();
    #pragma unroll 4
    for (int i = tid; i < 128 * KPS; i += 256) {
      int col = i / KPS, k = i - col * KPS;
      Wse_t[((size_t)n * 128 + col) * KPS + k] = (k < SD) ? T[k * 130 + col] : (u16)0;
    }
  } else {                              // Wp -> Wp_t [mat][col=p*32+d][KP]
    int pm = blk - 48, p = pm / 3, mat = pm - 3 * p;
    const void* W = (mat == 0) ? Wsl : (mat == 1) ? Wk : Wv;
    #pragma unroll 4
    for (int i = tid; i < 128 * 32; i += 256) {
      int kr = i >> 5, d = i & 31;
      T[kr * 34 + d] = ldbf(W, ((size_t)p * HID + kr) * ATT + d, bf);
    }
    __syncthreads();
    #pragma unroll 4
    for (int i = tid; i < 32 * KP; i += 256) {
      int d = i / KP, k = i - d * KP;
      Wp_t[((size_t)mat * HID + p * ATT + d) * KP + k] = (k < HID) ? T[k * 34 + d] : (u16)0;
    }
  }
}

// ---------------- K1b: fold BN stats partials once -> mst_g[8][80][2] ----------------
__global__ __launch_bounds__(256) void k_fin(const float* __restrict__ part, float* __restrict__ mst_g) {
  int n = blockIdx.x;
  int t = threadIdx.x;
  if (t < 160) {
    int col = t >> 1, half = t & 1;
    float S = 0.f, Q = 0.f;
    #pragma unroll
    for (int i = 0; i < 16; i++) {
      int c = half * 16 + i;
      const float* p = part + ((size_t)(n * 32 + c) * IND + col) * 2;
      S += p[0]; Q += p[1];
    }
    S += __shfl_xor(S, 1);
    Q += __shfl_xor(Q, 1);
    if (half == 0) {
      float mean = S * (1.f / BATCH);
      float var = Q * (1.f / BATCH) - mean * mean;
      mst_g[(size_t)n * IND * 2 + col * 2] = mean;
      mst_g[(size_t)n * IND * 2 + col * 2 + 1] = rsqrtf(var + EPS);
    }
  }
}

// ---------------- K2: fused encoders + col-split projections + attention ----------------
// 512 threads (8 waves), block = 16 batches x 8 agents. Wave w = agent w for the
// SE/E GEMMs; wave w = output cols [16w,16w+16) for the projections; wave w =
// batches 2w,2w+1 for attention.
// LDS: A 34816 + Bt 34816 + wb 6144 + mst 5120 = 80896 B -> 2 blocks/CU. 9 barriers.
__global__ __launch_bounds__(512, 4) void k_fused6(
    const void* __restrict__ s, const void* __restrict__ a,
    const u16* __restrict__ Wsa_t, const void* __restrict__ bsa,
    const u16* __restrict__ Wse_t, const void* __restrict__ bse,
    const u16* __restrict__ Wp_t, const void* __restrict__ bv_g,
    const float* __restrict__ mst_g, const int* __restrict__ flag,
    u16* __restrict__ SEo, u16* __restrict__ OT2) {
  __shared__ __align__(16) u16 A[128 * KP];    // sanb -> E -> KEYt (interleaved rows)
  __shared__ __align__(16) u16 Bt[128 * KP];   // SE -> SELt -> VALt (stride VTS3)
  __shared__ u16 wb[128 * WBS];                // softmax weights, wave-private rows
  __shared__ float mst[NA * 160];
  bool bf = (*flag != 0);
  int tid = threadIdx.x;
  int B0 = blockIdx.x * 16;
  int w = tid >> 6, lane = tid & 63, q = lane >> 4, rl = lane & 15;
  for (int i = tid; i < NA * 160; i += 512) mst[i] = mst_g[i];
  barlg();   // B0: mst ready
  // ---- stage bn(s|a) into A: row = agent*16 + bi ----
  for (int i = tid; i < 128 * 32; i += 512) {          // s-part k 0..63
    int row = i >> 5, kp = i & 31;
    int ag = row >> 4, bi = row & 15;
    float x0, x1;
    if (bf) { u32 wv = ((const u32*)s)[((size_t)ag * BATCH + B0 + bi) * 32 + kp]; x0 = lo2f(wv); x1 = hi2f(wv); }
    else { const float* sf = (const float*)s + ((size_t)ag * BATCH + B0 + bi) * 64 + 2 * kp; x0 = sf[0]; x1 = sf[1]; }
    int k = 2 * kp;
    const float* m = &mst[ag * 160];
    u32 o = (u32)f2bf((x0 - m[k * 2]) * m[k * 2 + 1]) |
            ((u32)f2bf((x1 - m[k * 2 + 2]) * m[k * 2 + 3]) << 16);
    *(u32*)&A[row * KP + k] = o;
  }
  for (int i = tid; i < 128 * 8; i += 512) {           // a-part k 64..79
    int row = i >> 3, kp = i & 7;
    int ag = row >> 4, bi = row & 15;
    float x0, x1;
    if (bf) { u32 wv = ((const u32*)a)[((size_t)ag * BATCH + B0 + bi) * 8 + kp]; x0 = lo2f(wv); x1 = hi2f(wv); }
    else { const float* af = (const float*)a + ((size_t)ag * BATCH + B0 + bi) * 16 + 2 * kp; x0 = af[0]; x1 = af[1]; }
    int k = SD + 2 * kp;
    const float* m = &mst[ag * 160];
    u32 o = (u32)f2bf((x0 - m[k * 2]) * m[k * 2 + 1]) |
            ((u32)f2bf((x1 - m[k * 2 + 2]) * m[k * 2 + 3]) << 16);
    *(u32*)&A[row * KP + k] = o;
  }
  for (int i = tid; i < 128 * 8; i += 512) {           // zero pad k 80..95
    int row = i >> 3, c2 = i & 7;
    *(u32*)&A[row * KP + IND + 2 * c2] = 0u;
  }
  barlg();   // B1: sanb staged
  const int n = w;   // wave's agent (SE/E phases)
  const u16* WS = Wse_t + (size_t)n * HID * KPS;
  const u16* WA = Wsa_t + (size_t)n * HID * KP3;
  // ---- SE acc (K=64) and E acc (K=96), wave-private rows ----
  float4f accS[8] = {};
  #pragma unroll
  for (int kc = 0; kc < 2; kc++) {
    short8 a0 = *(const short8*)&A[(w * 16 + rl) * KP + kc * 32 + q * 8];
    #pragma unroll
    for (int nt = 0; nt < 8; nt++) {
      short8 bb = *(const short8*)(WS + (size_t)(nt * 16 + rl) * KPS + kc * 32 + q * 8);
      accS[nt] = MFMA16(a0, bb, accS[nt]);
    }
  }
  float4f accE[8] = {};
  #pragma unroll
  for (int kc = 0; kc < 3; kc++) {
    short8 a0 = *(const short8*)&A[(w * 16 + rl) * KP + kc * 32 + q * 8];
    #pragma unroll
    for (int nt = 0; nt < 8; nt++) {
      short8 bb = *(const short8*)(WA + (size_t)(nt * 16 + rl) * KP3 + kc * 32 + q * 8);
      accE[nt] = MFMA16(a0, bb, accE[nt]);
    }
  }
  barlg();   // B2: all sanb reads done
  // ---- Bt <- SE (own rows) + SEo global; A <- E (own rows); accS/accE die ----
  #pragma unroll
  for (int nt = 0; nt < 8; nt++) {
    int col = nt * 16 + rl;
    float biasS = ldin(bse, n * HID + col, bf);
    float biasE = ldin(bsa, n * HID + col, bf);
    #pragma unroll
    for (int r = 0; r < 4; r++) {
      int bi = q * 4 + r;
      u16 v = f2bf(lrelu(accS[nt][r] + biasS));
      Bt[(w * 16 + bi) * KP + col] = v;
      SEo[((size_t)n * BATCH + B0 + bi) * HID + col] = v;
      A[(w * 16 + bi) * KP + col] = f2bf(lrelu(accE[nt][r] + biasE));
    }
  }
  const u16* WSL = Wp_t;                               // mat 0, [128 col][KP]
  const u16* WKm = Wp_t + (size_t)HID * KP;            // mat 1
  const u16* WVm = Wp_t + (size_t)2 * HID * KP;        // mat 2
  const int myc = w * 16 + rl;                         // this lane's output column
  // prefetch SEL weight frags BEFORE the barrier (in flight across it)
  short8 wsl[4];
  #pragma unroll
  for (int kc = 0; kc < 4; kc++)
    wsl[kc] = *(const short8*)(WSL + (size_t)myc * KP + kc * 32 + q * 8);
  barlg();   // B3: SE (Bt) and E (A) tiles fully visible to all waves
  // ---- phase SEL (col-split): pack to bf16 pairs BEFORE barrier ----
  {
    float4f aSL[8] = {};
    #pragma unroll
    for (int kc = 0; kc < 4; kc++) {
      #pragma unroll
      for (int mt = 0; mt < 8; mt++) {
        short8 af = lds_s8(&Bt[(mt * 16 + rl) * KP + kc * 32 + q * 8]);
        aSL[mt] = MFMA16(af, wsl[kc], aSL[mt]);
      }
    }
    u32 pk[16];
    #pragma unroll
    for (int mt = 0; mt < 8; mt++) {
      pk[2 * mt]     = (u32)f2bf(aSL[mt][0]) | ((u32)f2bf(aSL[mt][1]) << 16);
      pk[2 * mt + 1] = (u32)f2bf(aSL[mt][2]) | ((u32)f2bf(aSL[mt][3]) << 16);
    }
    barlg();   // B4: all Bt (SE) reads done  (only pk[16] live across)
    #pragma unroll
    for (int mt = 0; mt < 8; mt++)
      #pragma unroll
      for (int r = 0; r < 4; r++) {
        int iRow = (q * 4 + r) * 8 + mt;   // bi*8 + agent
        Bt[iRow * KP + myc] = (u16)(pk[2 * mt + (r >> 1)] >> ((r & 1) * 16));
      }
  }
  barlg();   // B5: SELt visible
  short8 saf[HEADS];
  #pragma unroll
  for (int p = 0; p < HEADS; p++)
    saf[p] = lds_s8(&Bt[(w * 16 + rl) * KP + p * ATT + q * 8]);
  barlg();   // B6: SELt reads done -> Bt space free
  // ---- phase VAL (col-split): retire transposed into Bt at stride VTS3 ----
  {
    float4f aV[8] = {};
    #pragma unroll
    for (int kc = 0; kc < 4; kc++) {
      short8 bv8 = *(const short8*)(WVm + (size_t)myc * KP + kc * 32 + q * 8);
      #pragma unroll
      for (int mt = 0; mt < 8; mt++) {
        short8 af = lds_s8(&A[(mt * 16 + rl) * KP + kc * 32 + q * 8]);
        aV[mt] = MFMA16(af, bv8, aV[mt]);
      }
    }
    float bvv = ldin(bv_g, myc, bf);
    #pragma unroll
    for (int mt = 0; mt < 8; mt++)
      #pragma unroll
      for (int r = 0; r < 4; r++) {
        int iRow = (q * 4 + r) * 8 + mt;
        Bt[myc * VTS3 + iRow] = f2bf(lrelu(aV[mt][r] + bvv));   // VALt [d][iRow]
      }
  }
  // ---- phase KEY (col-split): pack BEFORE barrier, retire into A ----
  {
    float4f aK[8] = {};
    #pragma unroll
    for (int kc = 0; kc < 4; kc++) {
      short8 bk = *(const short8*)(WKm + (size_t)myc * KP + kc * 32 + q * 8);
      #pragma unroll
      for (int mt = 0; mt < 8; mt++) {
        short8 af = lds_s8(&A[(mt * 16 + rl) * KP + kc * 32 + q * 8]);
        aK[mt] = MFMA16(af, bk, aK[mt]);
      }
    }
    u32 pk[16];
    #pragma unroll
    for (int mt = 0; mt < 8; mt++) {
      pk[2 * mt]     = (u32)f2bf(aK[mt][0]) | ((u32)f2bf(aK[mt][1]) << 16);
      pk[2 * mt + 1] = (u32)f2bf(aK[mt][2]) | ((u32)f2bf(aK[mt][3]) << 16);
    }
    barlg();   // B7: all A (E) reads done (VAL+KEY) -> A reusable
    #pragma unroll
    for (int mt = 0; mt < 8; mt++)
      #pragma unroll
      for (int r = 0; r < 4; r++) {
        int iRow = (q * 4 + r) * 8 + mt;
        A[iRow * KP + myc] = (u16)(pk[2 * mt + (r >> 1)] >> ((r & 1) * 16));
      }
  }
  barlg();   // B8: KEYt + VALt visible — attention reads only stable tiles
  // ---- attention: 4 heads, zero barriers (verified code) ----
  const float scale = 0.17677669529663687f;
  #pragma unroll
  for (int p = 0; p < HEADS; p++) {
    short8 sa = saf[p];
    short8 kb = lds_s8(&A[(w * 16 + rl) * KP + p * ATT + q * 8]);
    float4f zc = {};
    float4f c = MFMA16(sa, kb, zc);
    int nn = rl;
    #pragma unroll
    for (int r = 0; r < 4; r++) {
      int row = q * 4 + r;
      float x = c[r] * scale;
      if (row == nn) x = -1e9f;                    // self-mask (same b, i==j)
      float mx = x;
      mx = fmaxf(mx, __shfl_xor(mx, 1));
      mx = fmaxf(mx, __shfl_xor(mx, 2));
      mx = fmaxf(mx, __shfl_xor(mx, 4));
      float e = __expf(x - mx);
      float ssum = e;
      ssum += __shfl_xor(ssum, 1);
      ssum += __shfl_xor(ssum, 2);
      ssum += __shfl_xor(ssum, 4);
      float wv = e / ssum;
      if ((row >> 3) != (nn >> 3)) wv = 0.f;       // zero cross-b junk
      wb[(w * 16 + row) * WBS + nn] = f2bf(wv);    // wave-private rows
    }
    short8 aw;
    if (q < 2) aw = *(const short8*)&wb[(w * 16 + rl) * WBS + q * 8];
    else { short8 z = {}; aw = z; }
    float4f o[2] = {};
    #pragma unroll
    for (int nt = 0; nt < 2; nt++) {
      short8 bv8 = lds_s8(&Bt[(p * ATT + nt * 16 + rl) * VTS3 + w * 16 + (q & 1) * 8]);
      o[nt] = MFMA16(aw, bv8, o[nt]);
    }
    #pragma unroll
    for (int nt = 0; nt < 2; nt++)
      #pragma unroll
      for (int r = 0; r < 4; r++) {
        int row = q * 4 + r;
        int rp = w * 16 + (row >> 3) * 8 + (row & 7);   // interleaved b*8+agent
        OT2[((size_t)blockIdx.x * 128 + rp) * HID + p * ATT + nt * 16 + rl] = f2bf(o[nt][r]);
      }
  }
}

// ---------------- K4: critic — N-split GEMM, hoisted amax/wc2f, vector gather ----------------
// LDS: Xt 34816 + wc2f 8192 + bc1f 512 + amax 512 = 44032 B
__global__ __launch_bounds__(256) void k_critic2(
    const u16* __restrict__ SEi, const u16* __restrict__ OT, const void* __restrict__ a_g,
    const u16* __restrict__ Wc1t, const void* __restrict__ bc1_g,
    const void* __restrict__ Wc2_g, const void* __restrict__ bc2_g,
    const int* __restrict__ flag, void* __restrict__ qo) {
  __shared__ __align__(16) u16 Xt[128 * KP];   // input rows; reused as ht
  __shared__ float wc2f[HID * AD];
  __shared__ float bc1f[HID];
  __shared__ int amax[128];
  bool bf = (*flag != 0);
  int tid = threadIdx.x;
  int n = blockIdx.y;
  int b0 = blockIdx.x * 128;
  int w = tid >> 6, lane = tid & 63, q = lane >> 4, rl = lane & 15;
  if (tid < HID) bc1f[tid] = ldin(bc1_g, n * HID + tid, bf);
  // ---- amax hoisted to top: coalesced 16/32B loads + shfl combine ----
  {
    int b = tid >> 1, half = tid & 1;
    float best; int bi;
    if (bf) {
      const uint4v* pa = (const uint4v*)((const u32*)a_g + ((size_t)n * BATCH + b0 + b) * 8 + half * 4);
      uint4v x = *pa;
      float v[8] = {lo2f(x[0]), hi2f(x[0]), lo2f(x[1]), hi2f(x[1]),
                    lo2f(x[2]), hi2f(x[2]), lo2f(x[3]), hi2f(x[3])};
      best = v[0]; bi = 0;
      #pragma unroll
      for (int j = 1; j < 8; j++) if (v[j] > best) { best = v[j]; bi = j; }
    } else {
      const float* pa = (const float*)a_g + ((size_t)n * BATCH + b0 + b) * 16 + half * 8;
      float4f v0 = *(const float4f*)pa, v1 = *(const float4f*)(pa + 4);
      float v[8] = {v0[0], v0[1], v0[2], v0[3], v1[0], v1[1], v1[2], v1[3]};
      best = v[0]; bi = 0;
      #pragma unroll
      for (int j = 1; j < 8; j++) if (v[j] > best) { best = v[j]; bi = j; }
    }
    float ob = __shfl_xor(best, 1);
    int obi = __shfl_xor(bi, 1);
    if (half == 0) amax[b] = (ob > best) ? (obi + 8) : bi;   // strict > = first-max
  }
  // ---- wc2f staging hoisted (latency hides under GEMM staging) ----
  #pragma unroll 4
  for (int idx = tid; idx < HID * AD; idx += 256)
    wc2f[idx] = ldin(Wc2_g, (size_t)n * HID * AD + idx, bf);
  const u16* WT = Wc1t + (size_t)n * HID * 256;

  // ---- K=256 GEMM, N-split (wave owns 32 cols; B read once per block) ----
  float4f acc[8][2] = {};
  for (int ph = 0; ph < 2; ph++) {
    #pragma unroll 4
    for (int idx = tid; idx < 128 * 64; idx += 256) {
      int row = idx >> 6, c = idx & 63;
      u32 wv;
      if (ph == 0) wv = ((const u32*)SEi)[((size_t)n * BATCH + b0 + row) * 64 + c];
      else         wv = ((const u32*)OT)[((size_t)(b0 + row) * NA + n) * 64 + c];
      ((u32*)&Xt[row * KP])[c] = wv;
    }
    barlg();
    #pragma unroll
    for (int kc = 0; kc < 4; kc++) {
      int ko = ph * HID + kc * 32;
      short8 bb0 = *(const short8*)(WT + (size_t)(w * 32 + rl) * 256 + ko + q * 8);
      short8 bb1 = *(const short8*)(WT + (size_t)(w * 32 + 16 + rl) * 256 + ko + q * 8);
      #pragma unroll
      for (int mt = 0; mt < 8; mt++) {
        short8 af = *(const short8*)&Xt[(mt * 16 + rl) * KP + kc * 32 + q * 8];
        acc[mt][0] = MFMA16(af, bb0, acc[mt][0]);
        acc[mt][1] = MFMA16(af, bb1, acc[mt][1]);
      }
    }
    barlg();
  }
  u16* ht = Xt;
  #pragma unroll
  for (int mt = 0; mt < 8; mt++)
    #pragma unroll
    for (int nt = 0; nt < 2; nt++)
      #pragma unroll
      for (int r = 0; r < 4; r++) {
        int row = mt * 16 + q * 4 + r, col = w * 32 + nt * 16 + rl;
        ht[row * KP + col] = f2bf(lrelu(acc[mt][nt][r] + bc1f[col]));
      }
  barlg();
  {
    int b = tid >> 1, half = tid & 1;
    int col = amax[b];
    float acq = 0.f;
    const u16* hr = &ht[b * KP + half * 64];
    const float* wz = &wc2f[(half * 64) * AD + col];
    #pragma unroll
    for (int kk = 0; kk < 8; kk++) {
      short8 hv = lds_s8(hr + kk * 8);
      #pragma unroll
      for (int j = 0; j < 8; j++)
        acq = fmaf(bf2f((u16)hv[j]), wz[(kk * 8 + j) * AD], acq);
    }
    acq += __shfl_xor(acq, 1);
    if (half == 0) {
      float v = acq + ldin(bc2_g, n * AD + col, bf);
      size_t oidx = (size_t)n * BATCH + b0 + b;
      if (bf) ((u16*)qo)[oidx] = f2bf(v);
      else    ((float*)qo)[oidx] = v;
    }
  }
}

extern "C" void kernel_launch(void* const* d_in, const int* in_sizes, int n_in,
                              void* d_out, int out_size, void* d_ws, size_t ws_size,
                              hipStream_t stream) {
  const void* s   = d_in[0];
  const void* a   = d_in[1];
  const void* Wsa = d_in[2];
  const void* bsa = d_in[3];
  const void* Wse = d_in[4];
  const void* bse = d_in[5];
  const void* Wk  = d_in[6];
  const void* Wsl = d_in[7];
  const void* Wv  = d_in[8];
  const void* bv  = d_in[9];
  const void* Wc1 = d_in[10];
  const void* bc1 = d_in[11];
  const void* Wc2 = d_in[12];
  const void* bc2 = d_in[13];

  char* ws = (char*)d_ws;
  int*   flag  = (int*)ws;
  float* part  = (float*)(ws + 1024);
  float* mst_g = (float*)(ws + 1311744);
  u16*   Wsa_t = (u16*)(ws + 1316864);
  u16*   Wse_t = (u16*)(ws + 1529856);
  u16*   Wp_t  = (u16*)(ws + 1677312);
  u16*   Wc1t  = (u16*)(ws + 1781760);
  u16*   SEb   = (u16*)(ws + 2306048);
  u16*   OT2   = (u16*)(ws + 2306048 + 1ull * 33554432ull);

  k_prep<<<316, 256, 0, stream>>>(s, a, Wsa, Wse, Wsl, Wk, Wv, Wc1,
                                  flag, part, Wsa_t, Wse_t, Wp_t, Wc1t);
  k_fin<<<NA, 256, 0, stream>>>(part, mst_g);
  k_fused6<<<BATCH / 16, 512, 0, stream>>>(s, a, Wsa_t, bsa, Wse_t, bse, Wp_t, bv,
                                           mst_g, flag, SEb, OT2);
  k_critic2<<<dim3(BATCH / 128, NA), 256, 0, stream>>>(SEb, OT2, a, Wc1t, bc1, Wc2, bc2, flag, d_out);
}